// Round 1
// baseline (1063.046 us; speedup 1.0000x reference)
//
#include <hip/hip_runtime.h>
#include <math.h>

#define HID 64
#define NODE_DIM 74
#define LMOL 96
#define LSOLV 64
#define NPART 512

// ---------------- offsets / counts ----------------
__global__ void offsets_kernel(const int* mseg, const int* mpos, int Nm,
                               const int* sseg, const int* spos, int Ns,
                               int* moff, int* soff, int* mcnt, int* scnt) {
    int i = blockIdx.x * 256 + threadIdx.x;
    if (i < Nm) {
        int s = mseg[i], p = mpos[i];
        if (p == 0) moff[s] = i;
        atomicMax(&mcnt[s], p + 1);
    }
    if (i < Ns) {
        int s = sseg[i], p = spos[i];
        if (p == 0) soff[s] = i;
        atomicMax(&scnt[s], p + 1);
    }
}

// ---------------- solvent embedding: A = feats @ embW + embB ----------------
__global__ __launch_bounds__(256) void embed_kernel(const float* __restrict__ feats,
                                                    const float* __restrict__ W,
                                                    const float* __restrict__ bias,
                                                    float* __restrict__ out, int Ns) {
    __shared__ float Wl[NODE_DIM * HID];
    __shared__ float Fl[16 * NODE_DIM];
    int base = blockIdx.x * 16;
    int tid = threadIdx.x;
    for (int idx = tid; idx < NODE_DIM * HID; idx += 256) Wl[idx] = W[idx];
    int nrows = Ns - base; if (nrows > 16) nrows = 16;
    int nload = nrows * NODE_DIM;
    for (int idx = tid; idx < nload; idx += 256) Fl[idx] = feats[(size_t)base * NODE_DIM + idx];
    __syncthreads();
    int d = tid & 63, w = tid >> 6;
    float b = bias[d];
    for (int t = w; t < 16; t += 4) {
        int i = base + t;
        if (i >= Ns) break;
        float acc = b;
        #pragma unroll
        for (int k = 0; k < NODE_DIM; ++k)
            acc += Fl[t * NODE_DIM + k] * Wl[k * HID + d];
        out[(size_t)i * HID + d] = acc;
    }
}

// ---------------- one GCN layer: out = relu(agg @ W + b), agg = (self+prev+next)/3 ----------------
__global__ __launch_bounds__(256) void gcn_kernel(const float* __restrict__ in,
                                                  const float* __restrict__ W,
                                                  const float* __restrict__ bias,
                                                  const int* __restrict__ edst, int Ns,
                                                  float* __restrict__ out) {
    __shared__ float Wl[HID * HID];
    __shared__ float agg[16][HID];
    int base = blockIdx.x * 16;
    int tid = threadIdx.x;
    for (int idx = tid; idx < HID * HID; idx += 256) Wl[idx] = W[idx];
    int d = tid & 63, w = tid >> 6;
    for (int t = w; t < 16; t += 4) {
        int i = base + t;
        if (i >= Ns) break;
        int n1 = edst[Ns + i];
        int n2 = edst[2 * Ns + i];
        agg[t][d] = (in[(size_t)i * HID + d] + in[(size_t)n1 * HID + d] + in[(size_t)n2 * HID + d]) * (1.0f / 3.0f);
    }
    __syncthreads();
    float b = bias[d];
    for (int t = w; t < 16; t += 4) {
        int i = base + t;
        if (i >= Ns) break;
        float acc = b;
        #pragma unroll
        for (int k = 0; k < HID; ++k)
            acc += agg[t][k] * Wl[k * HID + d];
        out[(size_t)i * HID + d] = fmaxf(acc, 0.0f);
    }
}

// ---------------- stats over columns of X @ W (optionally storing Y) ----------------
template <bool STORE>
__global__ __launch_bounds__(256) void stats_kernel(const float* __restrict__ X,
                                                    const float* __restrict__ W, int N,
                                                    float* __restrict__ Y,
                                                    float* __restrict__ partial) {
    __shared__ float Wl[HID * HID];
    __shared__ float Xl[16 * HID];
    __shared__ float csum[HID], csq[HID];
    int tid = threadIdx.x;
    for (int idx = tid; idx < HID * HID; idx += 256) Wl[idx] = W[idx];
    if (tid < HID) { csum[tid] = 0.f; csq[tid] = 0.f; }
    int d = tid & 63, w = tid >> 6;
    float asum = 0.f, asq = 0.f;
    int ntiles = (N + 15) / 16;
    for (int tile = blockIdx.x; tile < ntiles; tile += gridDim.x) {
        int base = tile * 16;
        int nrows = N - base; if (nrows > 16) nrows = 16;
        int nload = nrows * HID;
        __syncthreads();
        for (int idx = tid; idx < nload; idx += 256) Xl[idx] = X[(size_t)base * HID + idx];
        __syncthreads();
        for (int t = w; t < 16; t += 4) {
            int i = base + t;
            if (i >= N) break;
            float acc = 0.f;
            #pragma unroll
            for (int k = 0; k < HID; ++k)
                acc += Xl[t * HID + k] * Wl[k * HID + d];
            if (STORE) Y[(size_t)i * HID + d] = acc;
            asum += acc; asq += acc * acc;
        }
    }
    atomicAdd(&csum[d], asum);
    atomicAdd(&csq[d], asq);
    __syncthreads();
    if (tid < HID) {
        partial[(size_t)blockIdx.x * 128 + tid] = csum[tid];
        partial[(size_t)blockIdx.x * 128 + 64 + tid] = csq[tid];
    }
}

// ---------------- finalize BN affine: scale/shift per column ----------------
__global__ void finalize_kernel(const float* __restrict__ partH, const float* __restrict__ partS,
                                int npart,
                                const float* __restrict__ gh, const float* __restrict__ bh,
                                const float* __restrict__ gs, const float* __restrict__ bs,
                                int Nm, int Ns, float* __restrict__ stats) {
    int tid = threadIdx.x;
    if (tid < 64) {
        float s = 0.f, q = 0.f;
        for (int b = 0; b < npart; ++b) { s += partH[b * 128 + tid]; q += partH[b * 128 + 64 + tid]; }
        float m = s / (float)Nm;
        float v = q / (float)Nm - m * m;
        float sc = gh[tid] * rsqrtf(v + 1e-5f);
        stats[tid] = sc;
        stats[64 + tid] = bh[tid] - m * sc;
    } else if (tid < 128) {
        int d = tid - 64;
        float s = 0.f, q = 0.f;
        for (int b = 0; b < npart; ++b) { s += partS[b * 128 + d]; q += partS[b * 128 + 64 + d]; }
        float m = s / (float)Ns;
        float v = q / (float)Ns - m * m;
        float sc = gs[d] * rsqrtf(v + 1e-5f);
        stats[128 + d] = sc;
        stats[192 + d] = bs[d] - m * sc;
    }
}

// ---------------- per-graph interaction + reductions -> z[B,256] ----------------
__global__ __launch_bounds__(256) void interact_kernel(
        const float* __restrict__ h, const float* __restrict__ hs, const float* __restrict__ ys,
        const float* __restrict__ hW, const float* __restrict__ stats,
        const int* __restrict__ moff, const int* __restrict__ mcnt,
        const int* __restrict__ soff, const int* __restrict__ scnt,
        float* __restrict__ Z) {
    __shared__ float hT[LMOL][HID + 1];   // h rows, then _h in place
    __shared__ float sT[LSOLV][HID + 1];  // _hs rows
    __shared__ float Wl[HID * HID];
    __shared__ float rs[LMOL], cs[LSOLV];
    __shared__ float zz[256];
    int g = blockIdx.x;
    int tid = threadIdx.x;
    int d = tid & 63, w = tid >> 6;
    int mo = moff[g], mc = mcnt[g], so = soff[g], sc = scnt[g];
    for (int idx = tid; idx < HID * HID; idx += 256) Wl[idx] = hW[idx];
    zz[tid] = 0.f;
    if (tid < LMOL) rs[tid] = 0.f;
    if (tid < LSOLV) cs[tid] = 0.f;
    float sch = stats[d], shh = stats[64 + d], scs = stats[128 + d], shs = stats[192 + d];
    // load h rows (+sum), zero-pad
    float hsum = 0.f;
    for (int m = w; m < LMOL; m += 4) {
        float v = (m < mc) ? h[(size_t)(mo + m) * HID + d] : 0.f;
        hT[m][d] = v;
        hsum += v;
    }
    // load _hs rows (affine on y_s), sum raw hs rows
    float ssum = 0.f;
    for (int n = w; n < LSOLV; n += 4) {
        float vy = 0.f;
        if (n < sc) {
            ssum += hs[(size_t)(so + n) * HID + d];
            vy = ys[(size_t)(so + n) * HID + d] * scs + shs;
        }
        sT[n][d] = vy;
    }
    __syncthreads();  // B1
    atomicAdd(&zz[d], hsum);
    atomicAdd(&zz[128 + d], ssum);
    // in-place _h = affine(h @ hW); wave w owns rows m == w (mod 4)
    for (int m = w; m < LMOL; m += 4) {
        float acc = 0.f;
        #pragma unroll
        for (int k = 0; k < HID; ++k)
            acc += hT[m][k] * Wl[k * HID + d];
        hT[m][d] = (m < mc) ? acc * sch + shh : 0.f;
    }
    __syncthreads();  // B2
    // QK^T + tanh + row/col sums. wave w covers n in [w*16, w*16+16)
    {
        int lane = tid & 63;
        int tm = lane & 15;
        int tnl = lane >> 4;
        int m0 = tm * 6;
        int n0 = w * 16 + tnl * 4;
        float acc[6][4];
        #pragma unroll
        for (int i = 0; i < 6; ++i)
            #pragma unroll
            for (int j = 0; j < 4; ++j) acc[i][j] = 0.f;
        if (w * 16 < sc) {  // whole-wave skip when its n-range is all padding
            #pragma unroll 4
            for (int k = 0; k < HID; ++k) {
                float a[6], bq[4];
                #pragma unroll
                for (int i = 0; i < 6; ++i) a[i] = hT[m0 + i][k];
                #pragma unroll
                for (int j = 0; j < 4; ++j) bq[j] = sT[n0 + j][k];
                #pragma unroll
                for (int i = 0; i < 6; ++i)
                    #pragma unroll
                    for (int j = 0; j < 4; ++j) acc[i][j] += a[i] * bq[j];
            }
            float rp[6] = {0.f, 0.f, 0.f, 0.f, 0.f, 0.f};
            float cp[4] = {0.f, 0.f, 0.f, 0.f};
            #pragma unroll
            for (int i = 0; i < 6; ++i) {
                #pragma unroll
                for (int j = 0; j < 4; ++j) {
                    float x = acc[i][j];
                    x = fminf(fmaxf(x, -15.f), 15.f);
                    float e = __expf(2.f * x);
                    float t = (e - 1.f) / (e + 1.f);   // tanh(x); pad entries are tanh(0)=0
                    rp[i] += t; cp[j] += t;
                }
            }
            #pragma unroll
            for (int i = 0; i < 6; ++i) atomicAdd(&rs[m0 + i], rp[i]);
            #pragma unroll
            for (int j = 0; j < 4; ++j) atomicAdd(&cs[n0 + j], cp[j]);
        }
    }
    __syncthreads();  // B3
    // z1 = cs . _hs ; z3 = rs . _h
    float p1 = 0.f, p3 = 0.f;
    for (int n = w; n < LSOLV; n += 4) p1 += cs[n] * sT[n][d];
    for (int m = w; m < LMOL; m += 4) p3 += rs[m] * hT[m][d];
    atomicAdd(&zz[64 + d], p1);
    atomicAdd(&zz[192 + d], p3);
    __syncthreads();  // B4
    Z[(size_t)g * 256 + tid] = zz[tid];
}

// ---------------- MLP: out = relu(z @ l1W + l1b) @ l2W + l2b ----------------
__global__ __launch_bounds__(256) void mlp_kernel(const float* __restrict__ Z,
                                                  const float* __restrict__ l1W,
                                                  const float* __restrict__ l1b,
                                                  const float* __restrict__ l2W,
                                                  const float* __restrict__ l2b,
                                                  float* __restrict__ out) {
    __shared__ float zl[16 * 256];
    __shared__ float red[64];
    int g0 = blockIdx.x * 16;
    int tid = threadIdx.x;
    for (int idx = tid; idx < 16 * 256; idx += 256) zl[idx] = Z[(size_t)g0 * 256 + idx];
    __syncthreads();
    float hid[16];
    float b = l1b[tid];
    #pragma unroll
    for (int t = 0; t < 16; ++t) hid[t] = b;
    for (int k = 0; k < 256; ++k) {
        float wv = l1W[k * 256 + tid];
        #pragma unroll
        for (int t = 0; t < 16; ++t) hid[t] += zl[t * 256 + k] * wv;
    }
    float w2 = l2W[tid];
    int lane = tid & 63, wv4 = tid >> 6;
    #pragma unroll
    for (int t = 0; t < 16; ++t) {
        float v = fmaxf(hid[t], 0.f) * w2;
        for (int off = 32; off; off >>= 1) v += __shfl_xor(v, off);
        if (lane == 0) red[wv4 * 16 + t] = v;
    }
    __syncthreads();
    if (tid < 16) out[g0 + tid] = red[tid] + red[16 + tid] + red[32 + tid] + red[48 + tid] + l2b[0];
}

extern "C" void kernel_launch(void* const* d_in, const int* in_sizes, int n_in,
                              void* d_out, int out_size, void* d_ws, size_t ws_size,
                              hipStream_t stream) {
    const float* h     = (const float*)d_in[0];
    const float* sfeat = (const float*)d_in[1];
    const float* embW  = (const float*)d_in[2];
    const float* embB  = (const float*)d_in[3];
    const float* gcnW  = (const float*)d_in[4];
    const float* gcnB  = (const float*)d_in[5];
    const float* hW    = (const float*)d_in[6];
    const float* sW    = (const float*)d_in[7];
    const float* bnhg  = (const float*)d_in[8];
    const float* bnhb  = (const float*)d_in[9];
    const float* bnsg  = (const float*)d_in[10];
    const float* bnsb  = (const float*)d_in[11];
    const float* l1W   = (const float*)d_in[12];
    const float* l1b   = (const float*)d_in[13];
    const float* l2W   = (const float*)d_in[14];
    const float* l2b   = (const float*)d_in[15];
    const int* mseg = (const int*)d_in[16];
    const int* mpos = (const int*)d_in[17];
    const int* sseg = (const int*)d_in[18];
    const int* spos = (const int*)d_in[19];
    const int* edst = (const int*)d_in[21];

    int Nm = in_sizes[0] / HID;
    int Ns = in_sizes[1] / NODE_DIM;
    int NB = out_size;  // 4096 graphs (TGT==1)

    float* ws    = (float*)d_ws;
    float* Abuf  = ws;
    float* Bbuf  = Abuf + (size_t)Ns * HID;
    float* Z     = Bbuf + (size_t)Ns * HID;
    int*   moff  = (int*)(Z + (size_t)NB * 256);
    int*   soff  = moff + NB;
    int*   mcnt  = soff + NB;
    int*   scnt  = mcnt + NB;
    float* partH = (float*)(scnt + NB);
    float* partS = partH + (size_t)NPART * 128;
    float* stats = partS + (size_t)NPART * 128;

    hipMemsetAsync(mcnt, 0, 2 * (size_t)NB * sizeof(int), stream);
    int nmax = Nm > Ns ? Nm : Ns;
    offsets_kernel<<<(nmax + 255) / 256, 256, 0, stream>>>(mseg, mpos, Nm, sseg, spos, Ns,
                                                           moff, soff, mcnt, scnt);
    int gblk = (Ns + 15) / 16;
    embed_kernel<<<gblk, 256, 0, stream>>>(sfeat, embW, embB, Abuf, Ns);
    const float* gin = Abuf;
    float* gout = Bbuf;
    for (int l = 0; l < 4; ++l) {
        gcn_kernel<<<gblk, 256, 0, stream>>>(gin, gcnW + l * HID * HID, gcnB + l * HID, edst, Ns, gout);
        float* t = (float*)gin; gin = gout; gout = t;
    }
    // final hs is in Abuf (gin), Bbuf (gout) free
    stats_kernel<false><<<NPART, 256, 0, stream>>>(h, hW, Nm, nullptr, partH);
    stats_kernel<true><<<NPART, 256, 0, stream>>>(gin, sW, Ns, gout, partS);
    finalize_kernel<<<1, 128, 0, stream>>>(partH, partS, NPART, bnhg, bnhb, bnsg, bnsb, Nm, Ns,
                                           (float*)stats);
    interact_kernel<<<NB, 256, 0, stream>>>(h, gin, gout, hW, stats, moff, mcnt, soff, scnt, Z);
    mlp_kernel<<<NB / 16, 256, 0, stream>>>(Z, l1W, l1b, l2W, l2b, (float*)d_out);
}

// Round 4
// 836.886 us; speedup vs baseline: 1.2702x; 1.2702x over previous
//
#include <hip/hip_runtime.h>
#include <math.h>

#define HID 64
#define NODE_DIM 74
#define LMOL 96
#define LSOLV 64
#define NPART 512
#define LDK 72      // padded LDS row stride (bf16) for K=64 tiles (144B = 9*16)
#define LDK96 104   // padded LDS row stride for K=96 tiles (208B = 13*16)

typedef __attribute__((ext_vector_type(8))) short short8;
typedef __attribute__((ext_vector_type(4))) float f32x4;
typedef unsigned short u16;
typedef unsigned int u32;

__device__ __forceinline__ u16 f2bf(float x) {
    u32 u = __float_as_uint(x);
    return (u16)((u + 0x7fffu + ((u >> 16) & 1u)) >> 16);
}
__device__ __forceinline__ float bf2f(u16 u) {
    return __uint_as_float(((u32)u) << 16);
}
// split x into hi/lo bf16 such that hi+lo ~ x to ~2^-17 rel
__device__ __forceinline__ void split_bf(float x, u16& hi, u16& lo) {
    hi = f2bf(x);
    lo = f2bf(x - bf2f(hi));
}

#define MFMA16(a, b, c) __builtin_amdgcn_mfma_f32_16x16x32_bf16((a), (b), (c), 0, 0, 0)

// ---------------- offsets / counts ----------------
__global__ void offsets_kernel(const int* mseg, const int* mpos, int Nm,
                               const int* sseg, const int* spos, int Ns,
                               int* moff, int* soff, int* mcnt, int* scnt) {
    int i = blockIdx.x * 256 + threadIdx.x;
    if (i < Nm) {
        int s = mseg[i], p = mpos[i];
        if (p == 0) moff[s] = i;
        atomicMax(&mcnt[s], p + 1);
    }
    if (i < Ns) {
        int s = sseg[i], p = spos[i];
        if (p == 0) soff[s] = i;
        atomicMax(&scnt[s], p + 1);
    }
}

// ---------------- solvent embedding via split-bf16 MFMA: out = feats @ embW + b ----------------
__global__ __launch_bounds__(256) void embed_mfma_kernel(const float* __restrict__ feats,
                                                         const float* __restrict__ W,
                                                         const float* __restrict__ bias,
                                                         float* __restrict__ out, int Ns) {
    __shared__ __align__(16) u16 sm[4 * 64 * LDK96];  // Ahi, Alo, Whi, Wlo
    u16* Ahi = sm;
    u16* Alo = sm + 64 * LDK96;
    u16* Whi = sm + 2 * 64 * LDK96;
    u16* Wlo = sm + 3 * 64 * LDK96;
    int tid = threadIdx.x;
    int base = blockIdx.x * 64;
    {   // zero all tiles (K padded 74 -> 96)
        u32* p = (u32*)sm;
        const int tot = (4 * 64 * LDK96) / 2;
        for (int idx = tid; idx < tot; idx += 256) p[idx] = 0u;
    }
    __syncthreads();
    for (int idx = tid; idx < NODE_DIM * 64; idx += 256) {
        int k = idx >> 6, n = idx & 63;
        u16 hi, lo; split_bf(W[idx], hi, lo);
        Whi[n * LDK96 + k] = hi; Wlo[n * LDK96 + k] = lo;
    }
    int nrows = Ns - base; if (nrows > 64) nrows = 64;
    for (int idx = tid; idx < nrows * NODE_DIM; idx += 256) {
        int r = idx / NODE_DIM, c = idx - r * NODE_DIM;
        u16 hi, lo; split_bf(feats[(size_t)base * NODE_DIM + idx], hi, lo);
        Ahi[r * LDK96 + c] = hi; Alo[r * LDK96 + c] = lo;
    }
    __syncthreads();
    int lane = tid & 63, w = tid >> 6;
    int lr = lane & 15, lg = lane >> 4;
    int r0 = w * 16;
    short8 ah[3], al[3];
    #pragma unroll
    for (int kc = 0; kc < 3; ++kc) {
        ah[kc] = *(const short8*)&Ahi[(r0 + lr) * LDK96 + kc * 32 + lg * 8];
        al[kc] = *(const short8*)&Alo[(r0 + lr) * LDK96 + kc * 32 + lg * 8];
    }
    #pragma unroll
    for (int nt = 0; nt < 4; ++nt) {
        int n0 = nt * 16;
        f32x4 acc = {0.f, 0.f, 0.f, 0.f};
        #pragma unroll
        for (int kc = 0; kc < 3; ++kc) {
            short8 bh = *(const short8*)&Whi[(n0 + lr) * LDK96 + kc * 32 + lg * 8];
            short8 bl = *(const short8*)&Wlo[(n0 + lr) * LDK96 + kc * 32 + lg * 8];
            acc = MFMA16(ah[kc], bh, acc);
            acc = MFMA16(al[kc], bh, acc);
            acc = MFMA16(ah[kc], bl, acc);
        }
        float bv = bias[n0 + lr];
        int col = n0 + lr;
        #pragma unroll
        for (int v = 0; v < 4; ++v) {
            int i = base + r0 + lg * 4 + v;
            if (i < Ns) out[(size_t)i * HID + col] = acc[v] + bv;
        }
    }
}

// ---------------- GCN layer via split-bf16 MFMA ----------------
__global__ __launch_bounds__(256) void gcn_mfma_kernel(const float* __restrict__ in,
                                                       const float* __restrict__ W,
                                                       const float* __restrict__ bias,
                                                       const int* __restrict__ edst, int Ns,
                                                       float* __restrict__ out) {
    __shared__ __align__(16) u16 Ahi[64][LDK], Alo[64][LDK], Whi[64][LDK], Wlo[64][LDK];
    int tid = threadIdx.x;
    int d = tid & 63, w = tid >> 6;
    int base = blockIdx.x * 64;
    #pragma unroll
    for (int t = 0; t < 16; ++t) {
        int k = w * 16 + t;
        u16 hi, lo; split_bf(W[k * HID + d], hi, lo);
        Whi[d][k] = hi; Wlo[d][k] = lo;
    }
    #pragma unroll
    for (int t = 0; t < 16; ++t) {
        int r = w + 4 * t;
        int i = base + r;
        float v = 0.f;
        if (i < Ns) {
            int n1 = edst[Ns + i], n2 = edst[2 * Ns + i];
            v = (in[(size_t)i * HID + d] + in[(size_t)n1 * HID + d] + in[(size_t)n2 * HID + d]) * (1.f / 3.f);
        }
        u16 hi, lo; split_bf(v, hi, lo);
        Ahi[r][d] = hi; Alo[r][d] = lo;
    }
    __syncthreads();
    int lane = tid & 63, lr = lane & 15, lg = lane >> 4;
    int r0 = w * 16;
    short8 ah0 = *(const short8*)&Ahi[r0 + lr][lg * 8];
    short8 ah1 = *(const short8*)&Ahi[r0 + lr][32 + lg * 8];
    short8 al0 = *(const short8*)&Alo[r0 + lr][lg * 8];
    short8 al1 = *(const short8*)&Alo[r0 + lr][32 + lg * 8];
    #pragma unroll
    for (int nt = 0; nt < 4; ++nt) {
        int n0 = nt * 16;
        short8 bh0 = *(const short8*)&Whi[n0 + lr][lg * 8];
        short8 bh1 = *(const short8*)&Whi[n0 + lr][32 + lg * 8];
        short8 bl0 = *(const short8*)&Wlo[n0 + lr][lg * 8];
        short8 bl1 = *(const short8*)&Wlo[n0 + lr][32 + lg * 8];
        f32x4 acc = {0.f, 0.f, 0.f, 0.f};
        acc = MFMA16(ah0, bh0, acc);
        acc = MFMA16(ah1, bh1, acc);
        acc = MFMA16(al0, bh0, acc);
        acc = MFMA16(al1, bh1, acc);
        acc = MFMA16(ah0, bl0, acc);
        acc = MFMA16(ah1, bl1, acc);
        float bv = bias[n0 + lr];
        int col = n0 + lr;
        #pragma unroll
        for (int v = 0; v < 4; ++v) {
            int i = base + r0 + lg * 4 + v;
            if (i < Ns) out[(size_t)i * HID + col] = fmaxf(acc[v] + bv, 0.f);
        }
    }
}

// ---------------- BN stats of X @ W via split-bf16 MFMA (optionally storing Y, f32) ----------------
template <bool STORE>
__global__ __launch_bounds__(256) void stats_mfma_kernel(const float* __restrict__ X,
                                                         const float* __restrict__ W, int N,
                                                         float* __restrict__ Y,
                                                         float* __restrict__ partial) {
    __shared__ __align__(16) u16 Ahi[64][LDK], Alo[64][LDK], Whi[64][LDK], Wlo[64][LDK];
    __shared__ float csum[64], csq[64];
    int tid = threadIdx.x;
    int d = tid & 63, w = tid >> 6;
    #pragma unroll
    for (int t = 0; t < 16; ++t) {
        int k = w * 16 + t;
        u16 hi, lo; split_bf(W[k * HID + d], hi, lo);
        Whi[d][k] = hi; Wlo[d][k] = lo;
    }
    if (tid < 64) { csum[tid] = 0.f; csq[tid] = 0.f; }
    __syncthreads();
    int lane = tid & 63, lr = lane & 15, lg = lane >> 4;
    int r0 = w * 16;
    float psum[4] = {0.f, 0.f, 0.f, 0.f}, psq[4] = {0.f, 0.f, 0.f, 0.f};
    int ntiles = (N + 63) / 64;
    for (int tile = blockIdx.x; tile < ntiles; tile += gridDim.x) {
        int base = tile * 64;
        __syncthreads();
        #pragma unroll
        for (int t = 0; t < 16; ++t) {
            int r = w + 4 * t, i = base + r;
            float v = (i < N) ? X[(size_t)i * HID + d] : 0.f;
            u16 hi, lo; split_bf(v, hi, lo);
            Ahi[r][d] = hi; Alo[r][d] = lo;
        }
        __syncthreads();
        short8 ah0 = *(const short8*)&Ahi[r0 + lr][lg * 8];
        short8 ah1 = *(const short8*)&Ahi[r0 + lr][32 + lg * 8];
        short8 al0 = *(const short8*)&Alo[r0 + lr][lg * 8];
        short8 al1 = *(const short8*)&Alo[r0 + lr][32 + lg * 8];
        int rem = N - base;
        #pragma unroll
        for (int nt = 0; nt < 4; ++nt) {
            int n0 = nt * 16;
            short8 bh0 = *(const short8*)&Whi[n0 + lr][lg * 8];
            short8 bh1 = *(const short8*)&Whi[n0 + lr][32 + lg * 8];
            short8 bl0 = *(const short8*)&Wlo[n0 + lr][lg * 8];
            short8 bl1 = *(const short8*)&Wlo[n0 + lr][32 + lg * 8];
            f32x4 acc = {0.f, 0.f, 0.f, 0.f};
            acc = MFMA16(ah0, bh0, acc);
            acc = MFMA16(ah1, bh1, acc);
            acc = MFMA16(al0, bh0, acc);
            acc = MFMA16(al1, bh1, acc);
            acc = MFMA16(ah0, bl0, acc);
            acc = MFMA16(ah1, bl1, acc);
            #pragma unroll
            for (int v = 0; v < 4; ++v) {
                int r = r0 + lg * 4 + v;
                if (r < rem) {
                    psum[nt] += acc[v]; psq[nt] += acc[v] * acc[v];
                    if (STORE) Y[(size_t)(base + r) * HID + n0 + lr] = acc[v];
                }
            }
        }
    }
    #pragma unroll
    for (int nt = 0; nt < 4; ++nt) {
        atomicAdd(&csum[nt * 16 + lr], psum[nt]);
        atomicAdd(&csq[nt * 16 + lr], psq[nt]);
    }
    __syncthreads();
    if (tid < 64) {
        partial[(size_t)blockIdx.x * 128 + tid] = csum[tid];
        partial[(size_t)blockIdx.x * 128 + 64 + tid] = csq[tid];
    }
}

// ---------------- finalize BN affine: scale/shift per column ----------------
__global__ void finalize_kernel(const float* __restrict__ partH, const float* __restrict__ partS,
                                int npart,
                                const float* __restrict__ gh, const float* __restrict__ bh,
                                const float* __restrict__ gs, const float* __restrict__ bs,
                                int Nm, int Ns, float* __restrict__ stats) {
    int tid = threadIdx.x;
    if (tid < 64) {
        float s = 0.f, q = 0.f;
        for (int b = 0; b < npart; ++b) { s += partH[b * 128 + tid]; q += partH[b * 128 + 64 + tid]; }
        float m = s / (float)Nm;
        float v = q / (float)Nm - m * m;
        float sc = gh[tid] * rsqrtf(v + 1e-5f);
        stats[tid] = sc;
        stats[64 + tid] = bh[tid] - m * sc;
    } else if (tid < 128) {
        int d = tid - 64;
        float s = 0.f, q = 0.f;
        for (int b = 0; b < npart; ++b) { s += partS[b * 128 + d]; q += partS[b * 128 + 64 + d]; }
        float m = s / (float)Ns;
        float v = q / (float)Ns - m * m;
        float sc = gs[d] * rsqrtf(v + 1e-5f);
        stats[128 + d] = sc;
        stats[192 + d] = bs[d] - m * sc;
    }
}

// ---------------- per-graph interaction + reductions -> z[B,256]  (round-1 f32, known-good) ----------------
__global__ __launch_bounds__(256) void interact_kernel(
        const float* __restrict__ h, const float* __restrict__ hs, const float* __restrict__ ys,
        const float* __restrict__ hW, const float* __restrict__ stats,
        const int* __restrict__ moff, const int* __restrict__ mcnt,
        const int* __restrict__ soff, const int* __restrict__ scnt,
        float* __restrict__ Z) {
    __shared__ float hT[LMOL][HID + 1];   // h rows, then _h in place
    __shared__ float sT[LSOLV][HID + 1];  // _hs rows
    __shared__ float Wl[HID * HID];
    __shared__ float rs[LMOL], cs[LSOLV];
    __shared__ float zz[256];
    int g = blockIdx.x;
    int tid = threadIdx.x;
    int d = tid & 63, w = tid >> 6;
    int mo = moff[g], mc = mcnt[g], so = soff[g], sc = scnt[g];
    for (int idx = tid; idx < HID * HID; idx += 256) Wl[idx] = hW[idx];
    zz[tid] = 0.f;
    if (tid < LMOL) rs[tid] = 0.f;
    if (tid < LSOLV) cs[tid] = 0.f;
    float sch = stats[d], shh = stats[64 + d], scs = stats[128 + d], shs = stats[192 + d];
    // load h rows (+sum), zero-pad
    float hsum = 0.f;
    for (int m = w; m < LMOL; m += 4) {
        float v = (m < mc) ? h[(size_t)(mo + m) * HID + d] : 0.f;
        hT[m][d] = v;
        hsum += v;
    }
    // load _hs rows (affine on y_s), sum raw hs rows
    float ssum = 0.f;
    for (int n = w; n < LSOLV; n += 4) {
        float vy = 0.f;
        if (n < sc) {
            ssum += hs[(size_t)(so + n) * HID + d];
            vy = ys[(size_t)(so + n) * HID + d] * scs + shs;
        }
        sT[n][d] = vy;
    }
    __syncthreads();  // B1
    atomicAdd(&zz[d], hsum);
    atomicAdd(&zz[128 + d], ssum);
    // in-place _h = affine(h @ hW); wave w owns rows m == w (mod 4)
    for (int m = w; m < LMOL; m += 4) {
        float acc = 0.f;
        #pragma unroll
        for (int k = 0; k < HID; ++k)
            acc += hT[m][k] * Wl[k * HID + d];
        hT[m][d] = (m < mc) ? acc * sch + shh : 0.f;
    }
    __syncthreads();  // B2
    // QK^T + tanh + row/col sums. wave w covers n in [w*16, w*16+16)
    {
        int lane = tid & 63;
        int tm = lane & 15;
        int tnl = lane >> 4;
        int m0 = tm * 6;
        int n0 = w * 16 + tnl * 4;
        float acc[6][4];
        #pragma unroll
        for (int i = 0; i < 6; ++i)
            #pragma unroll
            for (int j = 0; j < 4; ++j) acc[i][j] = 0.f;
        if (w * 16 < sc) {  // whole-wave skip when its n-range is all padding
            #pragma unroll 4
            for (int k = 0; k < HID; ++k) {
                float a[6], bq[4];
                #pragma unroll
                for (int i = 0; i < 6; ++i) a[i] = hT[m0 + i][k];
                #pragma unroll
                for (int j = 0; j < 4; ++j) bq[j] = sT[n0 + j][k];
                #pragma unroll
                for (int i = 0; i < 6; ++i)
                    #pragma unroll
                    for (int j = 0; j < 4; ++j) acc[i][j] += a[i] * bq[j];
            }
            float rp[6] = {0.f, 0.f, 0.f, 0.f, 0.f, 0.f};
            float cp[4] = {0.f, 0.f, 0.f, 0.f};
            #pragma unroll
            for (int i = 0; i < 6; ++i) {
                #pragma unroll
                for (int j = 0; j < 4; ++j) {
                    float x = acc[i][j];
                    x = fminf(fmaxf(x, -15.f), 15.f);
                    float e = __expf(2.f * x);
                    float t = (e - 1.f) / (e + 1.f);   // tanh(x); pad entries are tanh(0)=0
                    rp[i] += t; cp[j] += t;
                }
            }
            #pragma unroll
            for (int i = 0; i < 6; ++i) atomicAdd(&rs[m0 + i], rp[i]);
            #pragma unroll
            for (int j = 0; j < 4; ++j) atomicAdd(&cs[n0 + j], cp[j]);
        }
    }
    __syncthreads();  // B3
    // z1 = cs . _hs ; z3 = rs . _h
    float p1 = 0.f, p3 = 0.f;
    for (int n = w; n < LSOLV; n += 4) p1 += cs[n] * sT[n][d];
    for (int m = w; m < LMOL; m += 4) p3 += rs[m] * hT[m][d];
    atomicAdd(&zz[64 + d], p1);
    atomicAdd(&zz[192 + d], p3);
    __syncthreads();  // B4
    Z[(size_t)g * 256 + tid] = zz[tid];
}

// ---------------- MLP: out = relu(z @ l1W + l1b) @ l2W + l2b ----------------
__global__ __launch_bounds__(256) void mlp_kernel(const float* __restrict__ Z,
                                                  const float* __restrict__ l1W,
                                                  const float* __restrict__ l1b,
                                                  const float* __restrict__ l2W,
                                                  const float* __restrict__ l2b,
                                                  float* __restrict__ out) {
    __shared__ float zl[16 * 256];
    __shared__ float red[64];
    int g0 = blockIdx.x * 16;
    int tid = threadIdx.x;
    for (int idx = tid; idx < 16 * 256; idx += 256) zl[idx] = Z[(size_t)g0 * 256 + idx];
    __syncthreads();
    float hid[16];
    float b = l1b[tid];
    #pragma unroll
    for (int t = 0; t < 16; ++t) hid[t] = b;
    for (int k = 0; k < 256; ++k) {
        float wv = l1W[k * 256 + tid];
        #pragma unroll
        for (int t = 0; t < 16; ++t) hid[t] += zl[t * 256 + k] * wv;
    }
    float w2 = l2W[tid];
    int lane = tid & 63, wv4 = tid >> 6;
    #pragma unroll
    for (int t = 0; t < 16; ++t) {
        float v = fmaxf(hid[t], 0.f) * w2;
        for (int off = 32; off; off >>= 1) v += __shfl_xor(v, off);
        if (lane == 0) red[wv4 * 16 + t] = v;
    }
    __syncthreads();
    if (tid < 16) out[g0 + tid] = red[tid] + red[16 + tid] + red[32 + tid] + red[48 + tid] + l2b[0];
}

extern "C" void kernel_launch(void* const* d_in, const int* in_sizes, int n_in,
                              void* d_out, int out_size, void* d_ws, size_t ws_size,
                              hipStream_t stream) {
    const float* h     = (const float*)d_in[0];
    const float* sfeat = (const float*)d_in[1];
    const float* embW  = (const float*)d_in[2];
    const float* embB  = (const float*)d_in[3];
    const float* gcnW  = (const float*)d_in[4];
    const float* gcnB  = (const float*)d_in[5];
    const float* hW    = (const float*)d_in[6];
    const float* sW    = (const float*)d_in[7];
    const float* bnhg  = (const float*)d_in[8];
    const float* bnhb  = (const float*)d_in[9];
    const float* bnsg  = (const float*)d_in[10];
    const float* bnsb  = (const float*)d_in[11];
    const float* l1W   = (const float*)d_in[12];
    const float* l1b   = (const float*)d_in[13];
    const float* l2W   = (const float*)d_in[14];
    const float* l2b   = (const float*)d_in[15];
    const int* mseg = (const int*)d_in[16];
    const int* mpos = (const int*)d_in[17];
    const int* sseg = (const int*)d_in[18];
    const int* spos = (const int*)d_in[19];
    const int* edst = (const int*)d_in[21];

    int Nm = in_sizes[0] / HID;
    int Ns = in_sizes[1] / NODE_DIM;
    int NB = out_size;  // 4096 graphs (TGT==1)

    float* ws    = (float*)d_ws;
    float* Abuf  = ws;
    float* Bbuf  = Abuf + (size_t)Ns * HID;
    float* Z     = Bbuf + (size_t)Ns * HID;
    int*   moff  = (int*)(Z + (size_t)NB * 256);
    int*   soff  = moff + NB;
    int*   mcnt  = soff + NB;
    int*   scnt  = mcnt + NB;
    float* partH = (float*)(scnt + NB);
    float* partS = partH + (size_t)NPART * 128;
    float* statsbuf = partS + (size_t)NPART * 128;

    hipMemsetAsync(mcnt, 0, 2 * (size_t)NB * sizeof(int), stream);
    int nmax = Nm > Ns ? Nm : Ns;
    offsets_kernel<<<(nmax + 255) / 256, 256, 0, stream>>>(mseg, mpos, Nm, sseg, spos, Ns,
                                                           moff, soff, mcnt, scnt);
    int gblk = (Ns + 63) / 64;
    embed_mfma_kernel<<<gblk, 256, 0, stream>>>(sfeat, embW, embB, Abuf, Ns);
    const float* gin = Abuf;
    float* gout = Bbuf;
    for (int l = 0; l < 4; ++l) {
        gcn_mfma_kernel<<<gblk, 256, 0, stream>>>(gin, gcnW + l * HID * HID, gcnB + l * HID,
                                                  edst, Ns, gout);
        float* t = (float*)gin; gin = gout; gout = t;
    }
    // final hs in Abuf (gin); Bbuf (gout) free
    stats_mfma_kernel<false><<<NPART, 256, 0, stream>>>(h, hW, Nm, nullptr, partH);
    stats_mfma_kernel<true><<<NPART, 256, 0, stream>>>(gin, sW, Ns, gout, partS);
    finalize_kernel<<<1, 128, 0, stream>>>(partH, partS, NPART, bnhg, bnhb, bnsg, bnsb, Nm, Ns,
                                           statsbuf);
    interact_kernel<<<NB, 256, 0, stream>>>(h, gin, gout, hW, statsbuf, moff, mcnt, soff, scnt, Z);
    mlp_kernel<<<NB / 16, 256, 0, stream>>>(Z, l1W, l1b, l2W, l2b, (float*)d_out);
}

// Round 5
// 700.218 us; speedup vs baseline: 1.5182x; 1.1952x over previous
//
#include <hip/hip_runtime.h>
#include <math.h>

#define HID 64
#define NODE_DIM 74
#define LMOL 96
#define LSOLV 64
#define NPART 512
#define LDK 72      // padded LDS row stride (bf16) for K=64 tiles (144B = 9*16)
#define LDK96 104   // padded LDS row stride for K=96 tiles (208B = 13*16)

typedef __attribute__((ext_vector_type(8))) short short8;
typedef __attribute__((ext_vector_type(4))) float f32x4;
typedef unsigned short u16;
typedef unsigned int u32;

__device__ __forceinline__ u16 f2bf(float x) {
    u32 u = __float_as_uint(x);
    return (u16)((u + 0x7fffu + ((u >> 16) & 1u)) >> 16);
}
__device__ __forceinline__ float bf2f(u16 u) {
    return __uint_as_float(((u32)u) << 16);
}
// split x into hi/lo bf16 such that hi+lo ~ x to ~2^-17 rel
__device__ __forceinline__ void split_bf(float x, u16& hi, u16& lo) {
    hi = f2bf(x);
    lo = f2bf(x - bf2f(hi));
}

#define MFMA16(a, b, c) __builtin_amdgcn_mfma_f32_16x16x32_bf16((a), (b), (c), 0, 0, 0)

// ---------------- offsets / counts ----------------
__global__ void offsets_kernel(const int* mseg, const int* mpos, int Nm,
                               const int* sseg, const int* spos, int Ns,
                               int* moff, int* soff, int* mcnt, int* scnt) {
    int i = blockIdx.x * 256 + threadIdx.x;
    if (i < Nm) {
        int s = mseg[i], p = mpos[i];
        if (p == 0) moff[s] = i;
        atomicMax(&mcnt[s], p + 1);
    }
    if (i < Ns) {
        int s = sseg[i], p = spos[i];
        if (p == 0) soff[s] = i;
        atomicMax(&scnt[s], p + 1);
    }
}

// ---------------- solvent embedding via split-bf16 MFMA: out = feats @ embW + b ----------------
__global__ __launch_bounds__(256) void embed_mfma_kernel(const float* __restrict__ feats,
                                                         const float* __restrict__ W,
                                                         const float* __restrict__ bias,
                                                         float* __restrict__ out, int Ns) {
    __shared__ __align__(16) u16 sm[4 * 64 * LDK96];  // Ahi, Alo, Whi, Wlo
    u16* Ahi = sm;
    u16* Alo = sm + 64 * LDK96;
    u16* Whi = sm + 2 * 64 * LDK96;
    u16* Wlo = sm + 3 * 64 * LDK96;
    int tid = threadIdx.x;
    int base = blockIdx.x * 64;
    {   // zero all tiles (K padded 74 -> 96)
        u32* p = (u32*)sm;
        const int tot = (4 * 64 * LDK96) / 2;
        for (int idx = tid; idx < tot; idx += 256) p[idx] = 0u;
    }
    __syncthreads();
    for (int idx = tid; idx < NODE_DIM * 64; idx += 256) {
        int k = idx >> 6, n = idx & 63;
        u16 hi, lo; split_bf(W[idx], hi, lo);
        Whi[n * LDK96 + k] = hi; Wlo[n * LDK96 + k] = lo;
    }
    int nrows = Ns - base; if (nrows > 64) nrows = 64;
    for (int idx = tid; idx < nrows * NODE_DIM; idx += 256) {
        int r = idx / NODE_DIM, c = idx - r * NODE_DIM;
        u16 hi, lo; split_bf(feats[(size_t)base * NODE_DIM + idx], hi, lo);
        Ahi[r * LDK96 + c] = hi; Alo[r * LDK96 + c] = lo;
    }
    __syncthreads();
    int lane = tid & 63, w = tid >> 6;
    int lr = lane & 15, lg = lane >> 4;
    int r0 = w * 16;
    short8 ah[3], al[3];
    #pragma unroll
    for (int kc = 0; kc < 3; ++kc) {
        ah[kc] = *(const short8*)&Ahi[(r0 + lr) * LDK96 + kc * 32 + lg * 8];
        al[kc] = *(const short8*)&Alo[(r0 + lr) * LDK96 + kc * 32 + lg * 8];
    }
    #pragma unroll
    for (int nt = 0; nt < 4; ++nt) {
        int n0 = nt * 16;
        f32x4 acc = {0.f, 0.f, 0.f, 0.f};
        #pragma unroll
        for (int kc = 0; kc < 3; ++kc) {
            short8 bh = *(const short8*)&Whi[(n0 + lr) * LDK96 + kc * 32 + lg * 8];
            short8 bl = *(const short8*)&Wlo[(n0 + lr) * LDK96 + kc * 32 + lg * 8];
            acc = MFMA16(ah[kc], bh, acc);
            acc = MFMA16(al[kc], bh, acc);
            acc = MFMA16(ah[kc], bl, acc);
        }
        float bv = bias[n0 + lr];
        int col = n0 + lr;
        #pragma unroll
        for (int v = 0; v < 4; ++v) {
            int i = base + r0 + lg * 4 + v;
            if (i < Ns) out[(size_t)i * HID + col] = acc[v] + bv;
        }
    }
}

// ---------------- GCN layer via split-bf16 MFMA ----------------
__global__ __launch_bounds__(256) void gcn_mfma_kernel(const float* __restrict__ in,
                                                       const float* __restrict__ W,
                                                       const float* __restrict__ bias,
                                                       const int* __restrict__ edst, int Ns,
                                                       float* __restrict__ out) {
    __shared__ __align__(16) u16 Ahi[64][LDK], Alo[64][LDK], Whi[64][LDK], Wlo[64][LDK];
    int tid = threadIdx.x;
    int d = tid & 63, w = tid >> 6;
    int base = blockIdx.x * 64;
    #pragma unroll
    for (int t = 0; t < 16; ++t) {
        int k = w * 16 + t;
        u16 hi, lo; split_bf(W[k * HID + d], hi, lo);
        Whi[d][k] = hi; Wlo[d][k] = lo;
    }
    #pragma unroll
    for (int t = 0; t < 16; ++t) {
        int r = w + 4 * t;
        int i = base + r;
        float v = 0.f;
        if (i < Ns) {
            int n1 = edst[Ns + i], n2 = edst[2 * Ns + i];
            v = (in[(size_t)i * HID + d] + in[(size_t)n1 * HID + d] + in[(size_t)n2 * HID + d]) * (1.f / 3.f);
        }
        u16 hi, lo; split_bf(v, hi, lo);
        Ahi[r][d] = hi; Alo[r][d] = lo;
    }
    __syncthreads();
    int lane = tid & 63, lr = lane & 15, lg = lane >> 4;
    int r0 = w * 16;
    short8 ah0 = *(const short8*)&Ahi[r0 + lr][lg * 8];
    short8 ah1 = *(const short8*)&Ahi[r0 + lr][32 + lg * 8];
    short8 al0 = *(const short8*)&Alo[r0 + lr][lg * 8];
    short8 al1 = *(const short8*)&Alo[r0 + lr][32 + lg * 8];
    #pragma unroll
    for (int nt = 0; nt < 4; ++nt) {
        int n0 = nt * 16;
        short8 bh0 = *(const short8*)&Whi[n0 + lr][lg * 8];
        short8 bh1 = *(const short8*)&Whi[n0 + lr][32 + lg * 8];
        short8 bl0 = *(const short8*)&Wlo[n0 + lr][lg * 8];
        short8 bl1 = *(const short8*)&Wlo[n0 + lr][32 + lg * 8];
        f32x4 acc = {0.f, 0.f, 0.f, 0.f};
        acc = MFMA16(ah0, bh0, acc);
        acc = MFMA16(ah1, bh1, acc);
        acc = MFMA16(al0, bh0, acc);
        acc = MFMA16(al1, bh1, acc);
        acc = MFMA16(ah0, bl0, acc);
        acc = MFMA16(ah1, bl1, acc);
        float bv = bias[n0 + lr];
        int col = n0 + lr;
        #pragma unroll
        for (int v = 0; v < 4; ++v) {
            int i = base + r0 + lg * 4 + v;
            if (i < Ns) out[(size_t)i * HID + col] = fmaxf(acc[v] + bv, 0.f);
        }
    }
}

// ---------------- BN stats of X @ W via split-bf16 MFMA (optionally storing Y, f32) ----------------
template <bool STORE>
__global__ __launch_bounds__(256) void stats_mfma_kernel(const float* __restrict__ X,
                                                         const float* __restrict__ W, int N,
                                                         float* __restrict__ Y,
                                                         float* __restrict__ partial) {
    __shared__ __align__(16) u16 Ahi[64][LDK], Alo[64][LDK], Whi[64][LDK], Wlo[64][LDK];
    __shared__ float csum[64], csq[64];
    int tid = threadIdx.x;
    int d = tid & 63, w = tid >> 6;
    #pragma unroll
    for (int t = 0; t < 16; ++t) {
        int k = w * 16 + t;
        u16 hi, lo; split_bf(W[k * HID + d], hi, lo);
        Whi[d][k] = hi; Wlo[d][k] = lo;
    }
    if (tid < 64) { csum[tid] = 0.f; csq[tid] = 0.f; }
    __syncthreads();
    int lane = tid & 63, lr = lane & 15, lg = lane >> 4;
    int r0 = w * 16;
    float psum[4] = {0.f, 0.f, 0.f, 0.f}, psq[4] = {0.f, 0.f, 0.f, 0.f};
    int ntiles = (N + 63) / 64;
    for (int tile = blockIdx.x; tile < ntiles; tile += gridDim.x) {
        int base = tile * 64;
        __syncthreads();
        #pragma unroll
        for (int t = 0; t < 16; ++t) {
            int r = w + 4 * t, i = base + r;
            float v = (i < N) ? X[(size_t)i * HID + d] : 0.f;
            u16 hi, lo; split_bf(v, hi, lo);
            Ahi[r][d] = hi; Alo[r][d] = lo;
        }
        __syncthreads();
        short8 ah0 = *(const short8*)&Ahi[r0 + lr][lg * 8];
        short8 ah1 = *(const short8*)&Ahi[r0 + lr][32 + lg * 8];
        short8 al0 = *(const short8*)&Alo[r0 + lr][lg * 8];
        short8 al1 = *(const short8*)&Alo[r0 + lr][32 + lg * 8];
        int rem = N - base;
        #pragma unroll
        for (int nt = 0; nt < 4; ++nt) {
            int n0 = nt * 16;
            short8 bh0 = *(const short8*)&Whi[n0 + lr][lg * 8];
            short8 bh1 = *(const short8*)&Whi[n0 + lr][32 + lg * 8];
            short8 bl0 = *(const short8*)&Wlo[n0 + lr][lg * 8];
            short8 bl1 = *(const short8*)&Wlo[n0 + lr][32 + lg * 8];
            f32x4 acc = {0.f, 0.f, 0.f, 0.f};
            acc = MFMA16(ah0, bh0, acc);
            acc = MFMA16(ah1, bh1, acc);
            acc = MFMA16(al0, bh0, acc);
            acc = MFMA16(al1, bh1, acc);
            acc = MFMA16(ah0, bl0, acc);
            acc = MFMA16(ah1, bl1, acc);
            #pragma unroll
            for (int v = 0; v < 4; ++v) {
                int r = r0 + lg * 4 + v;
                if (r < rem) {
                    psum[nt] += acc[v]; psq[nt] += acc[v] * acc[v];
                    if (STORE) Y[(size_t)(base + r) * HID + n0 + lr] = acc[v];
                }
            }
        }
    }
    #pragma unroll
    for (int nt = 0; nt < 4; ++nt) {
        atomicAdd(&csum[nt * 16 + lr], psum[nt]);
        atomicAdd(&csq[nt * 16 + lr], psq[nt]);
    }
    __syncthreads();
    if (tid < 64) {
        partial[(size_t)blockIdx.x * 128 + tid] = csum[tid];
        partial[(size_t)blockIdx.x * 128 + 64 + tid] = csq[tid];
    }
}

// ---------------- finalize BN affine: scale/shift per column ----------------
__global__ void finalize_kernel(const float* __restrict__ partH, const float* __restrict__ partS,
                                int npart,
                                const float* __restrict__ gh, const float* __restrict__ bh,
                                const float* __restrict__ gs, const float* __restrict__ bs,
                                int Nm, int Ns, float* __restrict__ stats) {
    int tid = threadIdx.x;
    if (tid < 64) {
        float s = 0.f, q = 0.f;
        for (int b = 0; b < npart; ++b) { s += partH[b * 128 + tid]; q += partH[b * 128 + 64 + tid]; }
        float m = s / (float)Nm;
        float v = q / (float)Nm - m * m;
        float sc = gh[tid] * rsqrtf(v + 1e-5f);
        stats[tid] = sc;
        stats[64 + tid] = bh[tid] - m * sc;
    } else if (tid < 128) {
        int d = tid - 64;
        float s = 0.f, q = 0.f;
        for (int b = 0; b < npart; ++b) { s += partS[b * 128 + d]; q += partS[b * 128 + 64 + d]; }
        float m = s / (float)Ns;
        float v = q / (float)Ns - m * m;
        float sc = gs[d] * rsqrtf(v + 1e-5f);
        stats[128 + d] = sc;
        stats[192 + d] = bs[d] - m * sc;
    }
}

// ---------------- HYBRID interact: round-1 staging/_h (f32 scalar) + round-2 phase-4 MFMA ----------------
__global__ __launch_bounds__(256) void interact_kernel(
        const float* __restrict__ h, const float* __restrict__ hs, const float* __restrict__ ys,
        const float* __restrict__ hW, const float* __restrict__ stats,
        const int* __restrict__ moff, const int* __restrict__ mcnt,
        const int* __restrict__ soff, const int* __restrict__ scnt,
        float* __restrict__ Z) {
    __shared__ __align__(16) u16 hT[LMOL][LDK];   // bf16 raw h, then bf16 _h in place
    __shared__ __align__(16) u16 sT[LSOLV][LDK];  // bf16 _hs
    __shared__ float rs[LMOL], cs[LSOLV], zz[256];
    int g = blockIdx.x, tid = threadIdx.x;
    int d = tid & 63, w = tid >> 6;
    int lr = d & 15, lg = d >> 4;
    int mo = moff[g], mc = mcnt[g], so = soff[g], sc = scnt[g];
    zz[tid] = 0.f;
    if (tid < LMOL) rs[tid] = 0.f;
    if (tid < LSOLV) cs[tid] = 0.f;
    float sch = stats[d], shh = stats[64 + d], scs = stats[128 + d], shs = stats[192 + d];
    // hW column d cached in registers (L2-hot, coalesced across lanes)
    float wreg[64];
    #pragma unroll
    for (int k = 0; k < HID; ++k) wreg[k] = hW[k * HID + d];
    // stage raw h (bf16) + hsum
    float hsum = 0.f, ssum = 0.f;
    for (int m = w; m < LMOL; m += 4) {
        float v = (m < mc) ? h[(size_t)(mo + m) * HID + d] : 0.f;
        hT[m][d] = f2bf(v);
        hsum += v;
    }
    // stage _hs = affine(ys) (bf16) + ssum of raw hs
    for (int n = w; n < LSOLV; n += 4) {
        float vy = 0.f;
        if (n < sc) {
            ssum += hs[(size_t)(so + n) * HID + d];
            vy = ys[(size_t)(so + n) * HID + d] * scs + shs;
        }
        sT[n][d] = f2bf(vy);
    }
    __syncthreads();  // B1
    atomicAdd(&zz[d], hsum);
    atomicAdd(&zz[128 + d], ssum);
    // _h = affine(h @ hW), scalar f32; wave w owns rows m ≡ w (mod 4), in-place (round-1 pattern)
    for (int m = w; m < LMOL; m += 4) {
        float acc = 0.f;
        #pragma unroll
        for (int kk = 0; kk < 8; ++kk) {
            short8 hv = *(const short8*)&hT[m][kk * 8];
            #pragma unroll
            for (int j = 0; j < 8; ++j)
                acc = fmaf(bf2f((u16)hv[j]), wreg[kk * 8 + j], acc);
        }
        hT[m][d] = f2bf((m < mc) ? acc * sch + shh : 0.f);
    }
    __syncthreads();  // B2: _h/_hs tiles ready
    // phase 4 (under test): MFMA QK^T + tanh + row/col sums
    int col = w * 16 + lr;
    if (w * 16 < sc) {
        short8 b0 = *(const short8*)&sT[col][lg * 8];
        short8 b1 = *(const short8*)&sT[col][32 + lg * 8];
        float csacc = 0.f;
        for (int mt = 0; mt < 6; ++mt) {
            if (mt * 16 >= mc) break;  // mc uniform per block
            short8 a0 = *(const short8*)&hT[mt * 16 + lr][lg * 8];
            short8 a1 = *(const short8*)&hT[mt * 16 + lr][32 + lg * 8];
            f32x4 acc = {0.f, 0.f, 0.f, 0.f};
            acc = MFMA16(a0, b0, acc);
            acc = MFMA16(a1, b1, acc);
            #pragma unroll
            for (int v = 0; v < 4; ++v) {
                float x = acc[v];
                x = fminf(fmaxf(x, -15.f), 15.f);
                float e = __expf(2.f * x);
                float t = (e - 1.f) / (e + 1.f);  // tanh; pad entries give tanh(0)=0
                csacc += t;
                float rv = t;
                rv += __shfl_xor(rv, 1); rv += __shfl_xor(rv, 2);
                rv += __shfl_xor(rv, 4); rv += __shfl_xor(rv, 8);
                if (lr == 0) atomicAdd(&rs[mt * 16 + lg * 4 + v], rv);
            }
        }
        atomicAdd(&cs[col], csacc);
    }
    __syncthreads();  // B3
    // z1 = cs . _hs ; z3 = rs . _h
    float p1 = 0.f, p3 = 0.f;
    for (int n = w; n < LSOLV; n += 4) p1 += cs[n] * bf2f(sT[n][d]);
    for (int m = w; m < LMOL; m += 4) p3 += rs[m] * bf2f(hT[m][d]);
    atomicAdd(&zz[64 + d], p1);
    atomicAdd(&zz[192 + d], p3);
    __syncthreads();  // B4
    Z[(size_t)g * 256 + tid] = zz[tid];
}

// ---------------- MLP: out = relu(z @ l1W + l1b) @ l2W + l2b ----------------
__global__ __launch_bounds__(256) void mlp_kernel(const float* __restrict__ Z,
                                                  const float* __restrict__ l1W,
                                                  const float* __restrict__ l1b,
                                                  const float* __restrict__ l2W,
                                                  const float* __restrict__ l2b,
                                                  float* __restrict__ out) {
    __shared__ float zl[16 * 256];
    __shared__ float red[64];
    int g0 = blockIdx.x * 16;
    int tid = threadIdx.x;
    for (int idx = tid; idx < 16 * 256; idx += 256) zl[idx] = Z[(size_t)g0 * 256 + idx];
    __syncthreads();
    float hid[16];
    float b = l1b[tid];
    #pragma unroll
    for (int t = 0; t < 16; ++t) hid[t] = b;
    for (int k = 0; k < 256; ++k) {
        float wv = l1W[k * 256 + tid];
        #pragma unroll
        for (int t = 0; t < 16; ++t) hid[t] += zl[t * 256 + k] * wv;
    }
    float w2 = l2W[tid];
    int lane = tid & 63, wv4 = tid >> 6;
    #pragma unroll
    for (int t = 0; t < 16; ++t) {
        float v = fmaxf(hid[t], 0.f) * w2;
        for (int off = 32; off; off >>= 1) v += __shfl_xor(v, off);
        if (lane == 0) red[wv4 * 16 + t] = v;
    }
    __syncthreads();
    if (tid < 16) out[g0 + tid] = red[tid] + red[16 + tid] + red[32 + tid] + red[48 + tid] + l2b[0];
}

extern "C" void kernel_launch(void* const* d_in, const int* in_sizes, int n_in,
                              void* d_out, int out_size, void* d_ws, size_t ws_size,
                              hipStream_t stream) {
    const float* h     = (const float*)d_in[0];
    const float* sfeat = (const float*)d_in[1];
    const float* embW  = (const float*)d_in[2];
    const float* embB  = (const float*)d_in[3];
    const float* gcnW  = (const float*)d_in[4];
    const float* gcnB  = (const float*)d_in[5];
    const float* hW    = (const float*)d_in[6];
    const float* sW    = (const float*)d_in[7];
    const float* bnhg  = (const float*)d_in[8];
    const float* bnhb  = (const float*)d_in[9];
    const float* bnsg  = (const float*)d_in[10];
    const float* bnsb  = (const float*)d_in[11];
    const float* l1W   = (const float*)d_in[12];
    const float* l1b   = (const float*)d_in[13];
    const float* l2W   = (const float*)d_in[14];
    const float* l2b   = (const float*)d_in[15];
    const int* mseg = (const int*)d_in[16];
    const int* mpos = (const int*)d_in[17];
    const int* sseg = (const int*)d_in[18];
    const int* spos = (const int*)d_in[19];
    const int* edst = (const int*)d_in[21];

    int Nm = in_sizes[0] / HID;
    int Ns = in_sizes[1] / NODE_DIM;
    int NB = out_size;  // 4096 graphs (TGT==1)

    float* ws    = (float*)d_ws;
    float* Abuf  = ws;
    float* Bbuf  = Abuf + (size_t)Ns * HID;
    float* Z     = Bbuf + (size_t)Ns * HID;
    int*   moff  = (int*)(Z + (size_t)NB * 256);
    int*   soff  = moff + NB;
    int*   mcnt  = soff + NB;
    int*   scnt  = mcnt + NB;
    float* partH = (float*)(scnt + NB);
    float* partS = partH + (size_t)NPART * 128;
    float* statsbuf = partS + (size_t)NPART * 128;

    hipMemsetAsync(mcnt, 0, 2 * (size_t)NB * sizeof(int), stream);
    int nmax = Nm > Ns ? Nm : Ns;
    offsets_kernel<<<(nmax + 255) / 256, 256, 0, stream>>>(mseg, mpos, Nm, sseg, spos, Ns,
                                                           moff, soff, mcnt, scnt);
    int gblk = (Ns + 63) / 64;
    embed_mfma_kernel<<<gblk, 256, 0, stream>>>(sfeat, embW, embB, Abuf, Ns);
    const float* gin = Abuf;
    float* gout = Bbuf;
    for (int l = 0; l < 4; ++l) {
        gcn_mfma_kernel<<<gblk, 256, 0, stream>>>(gin, gcnW + l * HID * HID, gcnB + l * HID,
                                                  edst, Ns, gout);
        float* t = (float*)gin; gin = gout; gout = t;
    }
    // final hs in Abuf (gin); Bbuf (gout) free
    stats_mfma_kernel<false><<<NPART, 256, 0, stream>>>(h, hW, Nm, nullptr, partH);
    stats_mfma_kernel<true><<<NPART, 256, 0, stream>>>(gin, sW, Ns, gout, partS);
    finalize_kernel<<<1, 128, 0, stream>>>(partH, partS, NPART, bnhg, bnhb, bnsg, bnsb, Nm, Ns,
                                           statsbuf);
    interact_kernel<<<NB, 256, 0, stream>>>(h, gin, gout, hW, statsbuf, moff, mcnt, soff, scnt, Z);
    mlp_kernel<<<NB / 16, 256, 0, stream>>>(Z, l1W, l1b, l2W, l2b, (float*)d_out);
}

// Round 6
// 577.240 us; speedup vs baseline: 1.8416x; 1.2130x over previous
//
#include <hip/hip_runtime.h>
#include <math.h>

#define HID 64
#define NODE_DIM 74
#define LMOL 96
#define LSOLV 64
#define NPART 512
#define LDK 72      // padded LDS row stride (bf16) for K=64 tiles (144B = 9*16)
#define LDK96 104   // padded LDS row stride for K=96 tiles (208B = 13*16)

typedef __attribute__((ext_vector_type(8))) short short8;
typedef __attribute__((ext_vector_type(4))) float f32x4;
typedef unsigned short u16;
typedef unsigned int u32;

__device__ __forceinline__ u16 f2bf(float x) {
    u32 u = __float_as_uint(x);
    return (u16)((u + 0x7fffu + ((u >> 16) & 1u)) >> 16);
}
__device__ __forceinline__ float bf2f(u16 u) {
    return __uint_as_float(((u32)u) << 16);
}
// split x into hi/lo bf16 such that hi+lo ~ x to ~2^-17 rel
__device__ __forceinline__ void split_bf(float x, u16& hi, u16& lo) {
    hi = f2bf(x);
    lo = f2bf(x - bf2f(hi));
}

#define MFMA16(a, b, c) __builtin_amdgcn_mfma_f32_16x16x32_bf16((a), (b), (c), 0, 0, 0)

// ---------------- offsets / counts ----------------
__global__ void offsets_kernel(const int* mseg, const int* mpos, int Nm,
                               const int* sseg, const int* spos, int Ns,
                               int* moff, int* soff, int* mcnt, int* scnt) {
    int i = blockIdx.x * 256 + threadIdx.x;
    if (i < Nm) {
        int s = mseg[i], p = mpos[i];
        if (p == 0) moff[s] = i;
        atomicMax(&mcnt[s], p + 1);
    }
    if (i < Ns) {
        int s = sseg[i], p = spos[i];
        if (p == 0) soff[s] = i;
        atomicMax(&scnt[s], p + 1);
    }
}

// ---------------- solvent embedding via split-bf16 MFMA: out = feats @ embW + b (verified r4) ----------------
__global__ __launch_bounds__(256) void embed_mfma_kernel(const float* __restrict__ feats,
                                                         const float* __restrict__ W,
                                                         const float* __restrict__ bias,
                                                         float* __restrict__ out, int Ns) {
    __shared__ __align__(16) u16 sm[4 * 64 * LDK96];  // Ahi, Alo, Whi, Wlo
    u16* Ahi = sm;
    u16* Alo = sm + 64 * LDK96;
    u16* Whi = sm + 2 * 64 * LDK96;
    u16* Wlo = sm + 3 * 64 * LDK96;
    int tid = threadIdx.x;
    int base = blockIdx.x * 64;
    {   // zero all tiles (K padded 74 -> 96)
        u32* p = (u32*)sm;
        const int tot = (4 * 64 * LDK96) / 2;
        for (int idx = tid; idx < tot; idx += 256) p[idx] = 0u;
    }
    __syncthreads();
    for (int idx = tid; idx < NODE_DIM * 64; idx += 256) {
        int k = idx >> 6, n = idx & 63;
        u16 hi, lo; split_bf(W[idx], hi, lo);
        Whi[n * LDK96 + k] = hi; Wlo[n * LDK96 + k] = lo;
    }
    int nrows = Ns - base; if (nrows > 64) nrows = 64;
    for (int idx = tid; idx < nrows * NODE_DIM; idx += 256) {
        int r = idx / NODE_DIM, c = idx - r * NODE_DIM;
        u16 hi, lo; split_bf(feats[(size_t)base * NODE_DIM + idx], hi, lo);
        Ahi[r * LDK96 + c] = hi; Alo[r * LDK96 + c] = lo;
    }
    __syncthreads();
    int lane = tid & 63, w = tid >> 6;
    int lr = lane & 15, lg = lane >> 4;
    int r0 = w * 16;
    short8 ah[3], al[3];
    #pragma unroll
    for (int kc = 0; kc < 3; ++kc) {
        ah[kc] = *(const short8*)&Ahi[(r0 + lr) * LDK96 + kc * 32 + lg * 8];
        al[kc] = *(const short8*)&Alo[(r0 + lr) * LDK96 + kc * 32 + lg * 8];
    }
    #pragma unroll
    for (int nt = 0; nt < 4; ++nt) {
        int n0 = nt * 16;
        f32x4 acc = {0.f, 0.f, 0.f, 0.f};
        #pragma unroll
        for (int kc = 0; kc < 3; ++kc) {
            short8 bh = *(const short8*)&Whi[(n0 + lr) * LDK96 + kc * 32 + lg * 8];
            short8 bl = *(const short8*)&Wlo[(n0 + lr) * LDK96 + kc * 32 + lg * 8];
            acc = MFMA16(ah[kc], bh, acc);
            acc = MFMA16(al[kc], bh, acc);
            acc = MFMA16(ah[kc], bl, acc);
        }
        float bv = bias[n0 + lr];
        int col = n0 + lr;
        #pragma unroll
        for (int v = 0; v < 4; ++v) {
            int i = base + r0 + lg * 4 + v;
            if (i < Ns) out[(size_t)i * HID + col] = acc[v] + bv;
        }
    }
}

// ---------------- fused: GCN x4 + ys = hs@sW + solvent BN stats + per-graph hs_red ----------------
// one block per graph (sc <= 64 rows, self-contained ring)
__global__ __launch_bounds__(256) void gcn_fused_kernel(
        const float* __restrict__ hs0,      // embed output [Ns][64]
        const float* __restrict__ gcnW,     // [4][64][64]
        const float* __restrict__ gcnB,     // [4][64]
        const float* __restrict__ sW,       // [64][64]
        const int* __restrict__ soff, const int* __restrict__ scnt,
        float* __restrict__ ys, float* __restrict__ hs_red,
        float* __restrict__ sumS, float* __restrict__ sqS) {
    __shared__ __align__(16) u16 Ahi[64][LDK], Alo[64][LDK];   // current hs (split)
    __shared__ __align__(16) u16 Ghi[64][LDK], Glo[64][LDK];   // aggregated tile
    __shared__ __align__(16) u16 Whi[64][LDK], Wlo[64][LDK];   // weights (split, transposed)
    __shared__ float csum[64], csq[64];
    int g = blockIdx.x, tid = threadIdx.x;
    int d = tid & 63, w = tid >> 6;
    int lr = d & 15, lg = d >> 4;
    int so = soff[g], sc = scnt[g];
    if (tid < 64) { csum[tid] = 0.f; csq[tid] = 0.f; }
    // stage initial hs (pad rows -> 0)
    #pragma unroll
    for (int t = 0; t < 16; ++t) {
        int r = w + 4 * t;
        float v = (r < sc) ? hs0[(size_t)(so + r) * HID + d] : 0.f;
        u16 hi, lo; split_bf(v, hi, lo);
        Ahi[r][d] = hi; Alo[r][d] = lo;
    }
    for (int l = 0; l < 4; ++l) {
        const float* W = gcnW + l * HID * HID;
        __syncthreads();   // A stable; previous-layer W/G reads done
        // stage W_l (split, transposed: Whi[n][k] = W[k][n])
        #pragma unroll
        for (int t = 0; t < 16; ++t) {
            int k = w * 16 + t;
            u16 hi, lo; split_bf(W[k * HID + d], hi, lo);
            Whi[d][k] = hi; Wlo[d][k] = lo;
        }
        // aggregate ring: agg[r] = (A[r] + A[r-1 mod sc] + A[r+1 mod sc]) / 3
        #pragma unroll
        for (int t = 0; t < 16; ++t) {
            int r = w + 4 * t;
            float v = 0.f;
            if (r < sc) {
                int rp = (r == 0) ? sc - 1 : r - 1;
                int rn = (r + 1 == sc) ? 0 : r + 1;
                float a0 = bf2f(Ahi[r][d]) + bf2f(Alo[r][d]);
                float a1 = bf2f(Ahi[rp][d]) + bf2f(Alo[rp][d]);
                float a2 = bf2f(Ahi[rn][d]) + bf2f(Alo[rn][d]);
                v = (a0 + a1 + a2) * (1.f / 3.f);
            }
            u16 hi, lo; split_bf(v, hi, lo);
            Ghi[r][d] = hi; Glo[r][d] = lo;
        }
        __syncthreads();   // W and G ready
        // MFMA: A_new = relu(G @ W + b); wave w owns cols w*16..w*16+15
        int col = w * 16 + lr;
        float bv = gcnB[l * HID + col];
        short8 bh0 = *(const short8*)&Whi[col][lg * 8];
        short8 bh1 = *(const short8*)&Whi[col][32 + lg * 8];
        short8 bl0 = *(const short8*)&Wlo[col][lg * 8];
        short8 bl1 = *(const short8*)&Wlo[col][32 + lg * 8];
        #pragma unroll
        for (int rt = 0; rt < 4; ++rt) {
            short8 ah0 = *(const short8*)&Ghi[rt * 16 + lr][lg * 8];
            short8 ah1 = *(const short8*)&Ghi[rt * 16 + lr][32 + lg * 8];
            short8 al0 = *(const short8*)&Glo[rt * 16 + lr][lg * 8];
            short8 al1 = *(const short8*)&Glo[rt * 16 + lr][32 + lg * 8];
            f32x4 acc = {0.f, 0.f, 0.f, 0.f};
            acc = MFMA16(ah0, bh0, acc);
            acc = MFMA16(ah1, bh1, acc);
            acc = MFMA16(al0, bh0, acc);
            acc = MFMA16(al1, bh1, acc);
            acc = MFMA16(ah0, bl0, acc);
            acc = MFMA16(ah1, bl1, acc);
            #pragma unroll
            for (int v = 0; v < 4; ++v) {
                int row = rt * 16 + lg * 4 + v;
                float val = (row < sc) ? fmaxf(acc[v] + bv, 0.f) : 0.f;
                u16 hi, lo; split_bf(val, hi, lo);
                Ahi[row][col] = hi; Alo[row][col] = lo;
            }
        }
    }
    __syncthreads();   // final hs in A; last-layer W/G reads done
    // stage sW; hs_red partials
    #pragma unroll
    for (int t = 0; t < 16; ++t) {
        int k = w * 16 + t;
        u16 hi, lo; split_bf(sW[k * HID + d], hi, lo);
        Whi[d][k] = hi; Wlo[d][k] = lo;
    }
    {
        float loc = 0.f;
        #pragma unroll
        for (int t = 0; t < 16; ++t) {
            int r = w + 4 * t;
            if (r < sc) loc += bf2f(Ahi[r][d]) + bf2f(Alo[r][d]);
        }
        atomicAdd(&csum[d], loc);
    }
    __syncthreads();   // sW ready; csum = per-graph hs sum
    if (tid < 64) { hs_red[(size_t)g * 64 + tid] = csum[tid]; csum[tid] = 0.f; }
    __syncthreads();   // csum re-zeroed for ys stats
    // ys = hs @ sW (no bias); write global + column stats
    {
        int col = w * 16 + lr;
        short8 bh0 = *(const short8*)&Whi[col][lg * 8];
        short8 bh1 = *(const short8*)&Whi[col][32 + lg * 8];
        short8 bl0 = *(const short8*)&Wlo[col][lg * 8];
        short8 bl1 = *(const short8*)&Wlo[col][32 + lg * 8];
        float ps = 0.f, pq = 0.f;
        #pragma unroll
        for (int rt = 0; rt < 4; ++rt) {
            short8 ah0 = *(const short8*)&Ahi[rt * 16 + lr][lg * 8];
            short8 ah1 = *(const short8*)&Ahi[rt * 16 + lr][32 + lg * 8];
            short8 al0 = *(const short8*)&Alo[rt * 16 + lr][lg * 8];
            short8 al1 = *(const short8*)&Alo[rt * 16 + lr][32 + lg * 8];
            f32x4 acc = {0.f, 0.f, 0.f, 0.f};
            acc = MFMA16(ah0, bh0, acc);
            acc = MFMA16(ah1, bh1, acc);
            acc = MFMA16(al0, bh0, acc);
            acc = MFMA16(al1, bh1, acc);
            acc = MFMA16(ah0, bl0, acc);
            acc = MFMA16(ah1, bl1, acc);
            #pragma unroll
            for (int v = 0; v < 4; ++v) {
                int row = rt * 16 + lg * 4 + v;
                if (row < sc) {
                    float y = acc[v];
                    ys[(size_t)(so + row) * HID + col] = y;
                    ps += y; pq += y * y;
                }
            }
        }
        atomicAdd(&csum[col], ps);
        atomicAdd(&csq[col], pq);
    }
    __syncthreads();
    if (tid < 64) {
        atomicAdd(&sumS[tid], csum[tid]);
        atomicAdd(&sqS[tid], csq[tid]);
    }
}

// ---------------- BN stats of X @ W via split-bf16 MFMA, storing Y (verified r4) ----------------
template <bool STORE>
__global__ __launch_bounds__(256) void stats_mfma_kernel(const float* __restrict__ X,
                                                         const float* __restrict__ W, int N,
                                                         float* __restrict__ Y,
                                                         float* __restrict__ partial) {
    __shared__ __align__(16) u16 Ahi[64][LDK], Alo[64][LDK], Whi[64][LDK], Wlo[64][LDK];
    __shared__ float csum[64], csq[64];
    int tid = threadIdx.x;
    int d = tid & 63, w = tid >> 6;
    #pragma unroll
    for (int t = 0; t < 16; ++t) {
        int k = w * 16 + t;
        u16 hi, lo; split_bf(W[k * HID + d], hi, lo);
        Whi[d][k] = hi; Wlo[d][k] = lo;
    }
    if (tid < 64) { csum[tid] = 0.f; csq[tid] = 0.f; }
    __syncthreads();
    int lane = tid & 63, lr = lane & 15, lg = lane >> 4;
    int r0 = w * 16;
    float psum[4] = {0.f, 0.f, 0.f, 0.f}, psq[4] = {0.f, 0.f, 0.f, 0.f};
    int ntiles = (N + 63) / 64;
    for (int tile = blockIdx.x; tile < ntiles; tile += gridDim.x) {
        int base = tile * 64;
        __syncthreads();
        #pragma unroll
        for (int t = 0; t < 16; ++t) {
            int r = w + 4 * t, i = base + r;
            float v = (i < N) ? X[(size_t)i * HID + d] : 0.f;
            u16 hi, lo; split_bf(v, hi, lo);
            Ahi[r][d] = hi; Alo[r][d] = lo;
        }
        __syncthreads();
        short8 ah0 = *(const short8*)&Ahi[r0 + lr][lg * 8];
        short8 ah1 = *(const short8*)&Ahi[r0 + lr][32 + lg * 8];
        short8 al0 = *(const short8*)&Alo[r0 + lr][lg * 8];
        short8 al1 = *(const short8*)&Alo[r0 + lr][32 + lg * 8];
        int rem = N - base;
        #pragma unroll
        for (int nt = 0; nt < 4; ++nt) {
            int n0 = nt * 16;
            short8 bh0 = *(const short8*)&Whi[n0 + lr][lg * 8];
            short8 bh1 = *(const short8*)&Whi[n0 + lr][32 + lg * 8];
            short8 bl0 = *(const short8*)&Wlo[n0 + lr][lg * 8];
            short8 bl1 = *(const short8*)&Wlo[n0 + lr][32 + lg * 8];
            f32x4 acc = {0.f, 0.f, 0.f, 0.f};
            acc = MFMA16(ah0, bh0, acc);
            acc = MFMA16(ah1, bh1, acc);
            acc = MFMA16(al0, bh0, acc);
            acc = MFMA16(al1, bh1, acc);
            acc = MFMA16(ah0, bl0, acc);
            acc = MFMA16(ah1, bl1, acc);
            #pragma unroll
            for (int v = 0; v < 4; ++v) {
                int r = r0 + lg * 4 + v;
                if (r < rem) {
                    psum[nt] += acc[v]; psq[nt] += acc[v] * acc[v];
                    if (STORE) Y[(size_t)(base + r) * HID + n0 + lr] = acc[v];
                }
            }
        }
    }
    #pragma unroll
    for (int nt = 0; nt < 4; ++nt) {
        atomicAdd(&csum[nt * 16 + lr], psum[nt]);
        atomicAdd(&csq[nt * 16 + lr], psq[nt]);
    }
    __syncthreads();
    if (tid < 64) {
        partial[(size_t)blockIdx.x * 128 + tid] = csum[tid];
        partial[(size_t)blockIdx.x * 128 + 64 + tid] = csq[tid];
    }
}

// ---------------- finalize BN affine: h from partials, solvent from global accumulators ----------------
__global__ void finalize_kernel(const float* __restrict__ partH, int npart,
                                const float* __restrict__ sumS, const float* __restrict__ sqS,
                                const float* __restrict__ gh, const float* __restrict__ bh,
                                const float* __restrict__ gs, const float* __restrict__ bs,
                                int Nm, int Ns, float* __restrict__ stats) {
    int tid = threadIdx.x;
    if (tid < 64) {
        float s = 0.f, q = 0.f;
        for (int b = 0; b < npart; ++b) { s += partH[b * 128 + tid]; q += partH[b * 128 + 64 + tid]; }
        float m = s / (float)Nm;
        float v = q / (float)Nm - m * m;
        float sc = gh[tid] * rsqrtf(v + 1e-5f);
        stats[tid] = sc;
        stats[64 + tid] = bh[tid] - m * sc;
    } else if (tid < 128) {
        int d = tid - 64;
        float s = sumS[d], q = sqS[d];
        float m = s / (float)Ns;
        float v = q / (float)Ns - m * m;
        float sc = gs[d] * rsqrtf(v + 1e-5f);
        stats[128 + d] = sc;
        stats[192 + d] = bs[d] - m * sc;
    }
}

// ---------------- interact v2: affine-staged tiles + verified phase-4 MFMA -> z[B,256] ----------------
__global__ __launch_bounds__(256) void interact_kernel(
        const float* __restrict__ h, const float* __restrict__ yh,
        const float* __restrict__ ysb, const float* __restrict__ hs_red,
        const float* __restrict__ stats,
        const int* __restrict__ moff, const int* __restrict__ mcnt,
        const int* __restrict__ soff, const int* __restrict__ scnt,
        float* __restrict__ Z) {
    __shared__ __align__(16) u16 hT[LMOL][LDK];   // _h bf16
    __shared__ __align__(16) u16 sT[LSOLV][LDK];  // _hs bf16
    __shared__ float rs[LMOL], cs[LSOLV], zz[256];
    int g = blockIdx.x, tid = threadIdx.x;
    int d = tid & 63, w = tid >> 6;
    int lr = d & 15, lg = d >> 4;
    int mo = moff[g], mc = mcnt[g], so = soff[g], sc = scnt[g];
    zz[tid] = 0.f;
    if (tid < LMOL) rs[tid] = 0.f;
    if (tid < LSOLV) cs[tid] = 0.f;
    float sch = stats[d], shh = stats[64 + d], scs = stats[128 + d], shs = stats[192 + d];
    float hsum = 0.f;
    #pragma unroll
    for (int t = 0; t < 24; ++t) {
        int m = w + 4 * t;
        float vh = 0.f, vy = 0.f;
        if (m < mc) {
            vh = h[(size_t)(mo + m) * HID + d];
            vy = yh[(size_t)(mo + m) * HID + d] * sch + shh;
        }
        hT[m][d] = f2bf(vy);
        hsum += vh;
    }
    #pragma unroll
    for (int t = 0; t < 16; ++t) {
        int n = w + 4 * t;
        float vy = 0.f;
        if (n < sc) vy = ysb[(size_t)(so + n) * HID + d] * scs + shs;
        sT[n][d] = f2bf(vy);
    }
    __syncthreads();  // B1: _h/_hs tiles ready
    atomicAdd(&zz[d], hsum);
    if (w == 0) atomicAdd(&zz[128 + d], hs_red[(size_t)g * 64 + d]);
    // phase 4 (verified r5): MFMA QK^T + tanh + row/col sums
    int col = w * 16 + lr;
    if (w * 16 < sc) {
        short8 b0 = *(const short8*)&sT[col][lg * 8];
        short8 b1 = *(const short8*)&sT[col][32 + lg * 8];
        float csacc = 0.f;
        for (int mt = 0; mt < 6; ++mt) {
            if (mt * 16 >= mc) break;  // mc uniform per block
            short8 a0 = *(const short8*)&hT[mt * 16 + lr][lg * 8];
            short8 a1 = *(const short8*)&hT[mt * 16 + lr][32 + lg * 8];
            f32x4 acc = {0.f, 0.f, 0.f, 0.f};
            acc = MFMA16(a0, b0, acc);
            acc = MFMA16(a1, b1, acc);
            #pragma unroll
            for (int v = 0; v < 4; ++v) {
                float x = acc[v];
                x = fminf(fmaxf(x, -15.f), 15.f);
                float e = __expf(2.f * x);
                float t = (e - 1.f) / (e + 1.f);  // tanh; pad entries give tanh(0)=0
                csacc += t;
                float rv = t;
                rv += __shfl_xor(rv, 1); rv += __shfl_xor(rv, 2);
                rv += __shfl_xor(rv, 4); rv += __shfl_xor(rv, 8);
                if (lr == 0) atomicAdd(&rs[mt * 16 + lg * 4 + v], rv);
            }
        }
        atomicAdd(&cs[col], csacc);
    }
    __syncthreads();  // B2
    // z1 = cs . _hs ; z3 = rs . _h
    float p1 = 0.f, p3 = 0.f;
    for (int n = w; n < LSOLV; n += 4) p1 += cs[n] * bf2f(sT[n][d]);
    for (int m = w; m < LMOL; m += 4) p3 += rs[m] * bf2f(hT[m][d]);
    atomicAdd(&zz[64 + d], p1);
    atomicAdd(&zz[192 + d], p3);
    __syncthreads();  // B3
    Z[(size_t)g * 256 + tid] = zz[tid];
}

// ---------------- MLP: out = relu(z @ l1W + l1b) @ l2W + l2b ----------------
__global__ __launch_bounds__(256) void mlp_kernel(const float* __restrict__ Z,
                                                  const float* __restrict__ l1W,
                                                  const float* __restrict__ l1b,
                                                  const float* __restrict__ l2W,
                                                  const float* __restrict__ l2b,
                                                  float* __restrict__ out) {
    __shared__ float zl[16 * 256];
    __shared__ float red[64];
    int g0 = blockIdx.x * 16;
    int tid = threadIdx.x;
    for (int idx = tid; idx < 16 * 256; idx += 256) zl[idx] = Z[(size_t)g0 * 256 + idx];
    __syncthreads();
    float hid[16];
    float b = l1b[tid];
    #pragma unroll
    for (int t = 0; t < 16; ++t) hid[t] = b;
    for (int k = 0; k < 256; ++k) {
        float wv = l1W[k * 256 + tid];
        #pragma unroll
        for (int t = 0; t < 16; ++t) hid[t] += zl[t * 256 + k] * wv;
    }
    float w2 = l2W[tid];
    int lane = tid & 63, wv4 = tid >> 6;
    #pragma unroll
    for (int t = 0; t < 16; ++t) {
        float v = fmaxf(hid[t], 0.f) * w2;
        for (int off = 32; off; off >>= 1) v += __shfl_xor(v, off);
        if (lane == 0) red[wv4 * 16 + t] = v;
    }
    __syncthreads();
    if (tid < 16) out[g0 + tid] = red[tid] + red[16 + tid] + red[32 + tid] + red[48 + tid] + l2b[0];
}

extern "C" void kernel_launch(void* const* d_in, const int* in_sizes, int n_in,
                              void* d_out, int out_size, void* d_ws, size_t ws_size,
                              hipStream_t stream) {
    const float* h     = (const float*)d_in[0];
    const float* sfeat = (const float*)d_in[1];
    const float* embW  = (const float*)d_in[2];
    const float* embB  = (const float*)d_in[3];
    const float* gcnW  = (const float*)d_in[4];
    const float* gcnB  = (const float*)d_in[5];
    const float* hW    = (const float*)d_in[6];
    const float* sW    = (const float*)d_in[7];
    const float* bnhg  = (const float*)d_in[8];
    const float* bnhb  = (const float*)d_in[9];
    const float* bnsg  = (const float*)d_in[10];
    const float* bnsb  = (const float*)d_in[11];
    const float* l1W   = (const float*)d_in[12];
    const float* l1b   = (const float*)d_in[13];
    const float* l2W   = (const float*)d_in[14];
    const float* l2b   = (const float*)d_in[15];
    const int* mseg = (const int*)d_in[16];
    const int* mpos = (const int*)d_in[17];
    const int* sseg = (const int*)d_in[18];
    const int* spos = (const int*)d_in[19];

    int Nm = in_sizes[0] / HID;
    int Ns = in_sizes[1] / NODE_DIM;
    int NB = out_size;  // 4096 graphs (TGT==1)

    float* ws     = (float*)d_ws;
    float* yh     = ws;                          // [Nm][64]; prefix [Ns][64] doubles as embed out
    float* hsbuf  = ws;                          // alias (embed out, consumed before yh written)
    float* ysbuf  = yh + (size_t)Nm * HID;       // [Ns][64]
    float* hs_red = ysbuf + (size_t)Ns * HID;    // [NB][64]
    float* Z      = hs_red + (size_t)NB * 64;    // [NB][256]
    int*   moff   = (int*)(Z + (size_t)NB * 256);
    int*   soff   = moff + NB;
    int*   mcnt   = soff + NB;
    int*   scnt   = mcnt + NB;
    float* partH  = (float*)(scnt + NB);         // [NPART][128]
    float* sumS   = partH + (size_t)NPART * 128; // [64]
    float* sqS    = sumS + 64;                   // [64]
    float* statsbuf = sqS + 64;                  // [256]

    hipMemsetAsync(mcnt, 0, 2 * (size_t)NB * sizeof(int), stream);
    hipMemsetAsync(sumS, 0, 128 * sizeof(float), stream);
    int nmax = Nm > Ns ? Nm : Ns;
    offsets_kernel<<<(nmax + 255) / 256, 256, 0, stream>>>(mseg, mpos, Nm, sseg, spos, Ns,
                                                           moff, soff, mcnt, scnt);
    int gblk = (Ns + 63) / 64;
    embed_mfma_kernel<<<gblk, 256, 0, stream>>>(sfeat, embW, embB, hsbuf, Ns);
    gcn_fused_kernel<<<NB, 256, 0, stream>>>(hsbuf, gcnW, gcnB, sW, soff, scnt,
                                             ysbuf, hs_red, sumS, sqS);
    stats_mfma_kernel<true><<<NPART, 256, 0, stream>>>(h, hW, Nm, yh, partH);
    finalize_kernel<<<1, 128, 0, stream>>>(partH, NPART, sumS, sqS,
                                           bnhg, bnhb, bnsg, bnsb, Nm, Ns, statsbuf);
    interact_kernel<<<NB, 256, 0, stream>>>(h, yh, ysbuf, hs_red, statsbuf,
                                            moff, mcnt, soff, scnt, Z);
    mlp_kernel<<<NB / 16, 256, 0, stream>>>(Z, l1W, l1b, l2W, l2b, (float*)d_out);
}

// Round 8
// 530.000 us; speedup vs baseline: 2.0057x; 1.0891x over previous
//
#include <hip/hip_runtime.h>
#include <math.h>

#define HID 64
#define NODE_DIM 74
#define LMOL 96
#define LSOLV 64
#define NPART 512
#define LDK 72      // padded LDS row stride (bf16) for K=64 tiles (144B = 9*16)
#define LDK96 104   // padded LDS row stride for K=96 tiles (208B = 13*16)

typedef __attribute__((ext_vector_type(8))) short short8;
typedef __attribute__((ext_vector_type(4))) float f32x4;
typedef unsigned short u16;
typedef unsigned int u32;

__device__ __forceinline__ u16 f2bf(float x) {
    u32 u = __float_as_uint(x);
    return (u16)((u + 0x7fffu + ((u >> 16) & 1u)) >> 16);
}
__device__ __forceinline__ float bf2f(u16 u) {
    return __uint_as_float(((u32)u) << 16);
}
__device__ __forceinline__ void split_bf(float x, u16& hi, u16& lo) {
    hi = f2bf(x);
    lo = f2bf(x - bf2f(hi));
}

#define MFMA16(a, b, c) __builtin_amdgcn_mfma_f32_16x16x32_bf16((a), (b), (c), 0, 0, 0)

// ---------------- offsets / counts ----------------
__global__ void offsets_kernel(const int* mseg, const int* mpos, int Nm,
                               const int* sseg, const int* spos, int Ns,
                               int* moff, int* soff, int* mcnt, int* scnt) {
    int i = blockIdx.x * 256 + threadIdx.x;
    if (i < Nm) {
        int s = mseg[i], p = mpos[i];
        if (p == 0) moff[s] = i;
        atomicMax(&mcnt[s], p + 1);
    }
    if (i < Ns) {
        int s = sseg[i], p = spos[i];
        if (p == 0) soff[s] = i;
        atomicMax(&scnt[s], p + 1);
    }
}

// ---------------- solvent embedding via split-bf16 MFMA (verified r4/r5/r6) ----------------
__global__ __launch_bounds__(256) void embed_mfma_kernel(const float* __restrict__ feats,
                                                         const float* __restrict__ W,
                                                         const float* __restrict__ bias,
                                                         float* __restrict__ out, int Ns) {
    __shared__ __align__(16) u16 sm[4 * 64 * LDK96];  // Ahi, Alo, Whi, Wlo
    u16* Ahi = sm;
    u16* Alo = sm + 64 * LDK96;
    u16* Whi = sm + 2 * 64 * LDK96;
    u16* Wlo = sm + 3 * 64 * LDK96;
    int tid = threadIdx.x;
    int base = blockIdx.x * 64;
    {   // zero all tiles (K padded 74 -> 96)
        u32* p = (u32*)sm;
        const int tot = (4 * 64 * LDK96) / 2;
        for (int idx = tid; idx < tot; idx += 256) p[idx] = 0u;
    }
    __syncthreads();
    for (int idx = tid; idx < NODE_DIM * 64; idx += 256) {
        int k = idx >> 6, n = idx & 63;
        u16 hi, lo; split_bf(W[idx], hi, lo);
        Whi[n * LDK96 + k] = hi; Wlo[n * LDK96 + k] = lo;
    }
    int nrows = Ns - base; if (nrows > 64) nrows = 64;
    for (int idx = tid; idx < nrows * NODE_DIM; idx += 256) {
        int r = idx / NODE_DIM, c = idx - r * NODE_DIM;
        u16 hi, lo; split_bf(feats[(size_t)base * NODE_DIM + idx], hi, lo);
        Ahi[r * LDK96 + c] = hi; Alo[r * LDK96 + c] = lo;
    }
    __syncthreads();
    int lane = tid & 63, w = tid >> 6;
    int lr = lane & 15, lg = lane >> 4;
    int r0 = w * 16;
    short8 ah[3], al[3];
    #pragma unroll
    for (int kc = 0; kc < 3; ++kc) {
        ah[kc] = *(const short8*)&Ahi[(r0 + lr) * LDK96 + kc * 32 + lg * 8];
        al[kc] = *(const short8*)&Alo[(r0 + lr) * LDK96 + kc * 32 + lg * 8];
    }
    #pragma unroll
    for (int nt = 0; nt < 4; ++nt) {
        int n0 = nt * 16;
        f32x4 acc = {0.f, 0.f, 0.f, 0.f};
        #pragma unroll
        for (int kc = 0; kc < 3; ++kc) {
            short8 bh = *(const short8*)&Whi[(n0 + lr) * LDK96 + kc * 32 + lg * 8];
            short8 bl = *(const short8*)&Wlo[(n0 + lr) * LDK96 + kc * 32 + lg * 8];
            acc = MFMA16(ah[kc], bh, acc);
            acc = MFMA16(al[kc], bh, acc);
            acc = MFMA16(ah[kc], bl, acc);
        }
        float bv = bias[n0 + lr];
        int col = n0 + lr;
        #pragma unroll
        for (int v = 0; v < 4; ++v) {
            int i = base + r0 + lg * 4 + v;
            if (i < Ns) out[(size_t)i * HID + col] = acc[v] + bv;
        }
    }
}

// ---------------- fused GCN x4 + ys = hs@sW + solvent BN stats + hs_red (r6 numerics) ----------------
// W fragments preloaded to registers (identical split values / MFMA order as r6's LDS path)
__global__ __launch_bounds__(256, 3) void gcn_fused_kernel(
        const float* __restrict__ hs0,      // embed output [Ns][64]
        const float* __restrict__ gcnW,     // [4][64][64]
        const float* __restrict__ gcnB,     // [4][64]
        const float* __restrict__ sW,       // [64][64]
        const int* __restrict__ soff, const int* __restrict__ scnt,
        float* __restrict__ ys, float* __restrict__ hs_red,
        float* __restrict__ sumP) {
    __shared__ __align__(16) u16 Ahi[64][LDK], Alo[64][LDK];   // current hs (split)
    __shared__ __align__(16) u16 Ghi[64][LDK], Glo[64][LDK];   // aggregated tile / sW (late)
    __shared__ float csum[64], csq[64];
    int g = blockIdx.x, tid = threadIdx.x;
    int d = tid & 63, w = tid >> 6;
    int lr = d & 15, lg = d >> 4;
    int so = soff[g], sc = scnt[g];
    int col = w * 16 + lr;
    // preload split W fragments for the 4 GCN layers (wave w owns cols w*16..+15)
    short8 bh[4][2], bl[4][2];
    #pragma unroll
    for (int l = 0; l < 4; ++l) {
        const float* W = gcnW + l * HID * HID;
        #pragma unroll
        for (int half = 0; half < 2; ++half) {
            short8 vh, vl;
            #pragma unroll
            for (int j = 0; j < 8; ++j) {
                u16 hi, lo; split_bf(W[(half * 32 + lg * 8 + j) * HID + col], hi, lo);
                vh[j] = (short)hi; vl[j] = (short)lo;
            }
            bh[l][half] = vh; bl[l][half] = vl;
        }
    }
    if (tid < 64) { csum[tid] = 0.f; csq[tid] = 0.f; }
    // stage initial hs split (pad rows -> 0)
    #pragma unroll
    for (int t = 0; t < 16; ++t) {
        int r = w + 4 * t;
        float v = (r < sc) ? hs0[(size_t)(so + r) * HID + d] : 0.f;
        u16 hi, lo; split_bf(v, hi, lo);
        Ahi[r][d] = hi; Alo[r][d] = lo;
    }
    #pragma unroll
    for (int l = 0; l < 4; ++l) {
        __syncthreads();   // A stable; previous G reads done
        // aggregate ring: agg[r] = (A[r] + A[r-1 mod sc] + A[r+1 mod sc]) / 3 (split)
        #pragma unroll
        for (int t = 0; t < 16; ++t) {
            int r = w + 4 * t;
            float v = 0.f;
            if (r < sc) {
                int rp = (r == 0) ? sc - 1 : r - 1;
                int rn = (r + 1 == sc) ? 0 : r + 1;
                float a0 = bf2f(Ahi[r][d]) + bf2f(Alo[r][d]);
                float a1 = bf2f(Ahi[rp][d]) + bf2f(Alo[rp][d]);
                float a2 = bf2f(Ahi[rn][d]) + bf2f(Alo[rn][d]);
                v = (a0 + a1 + a2) * (1.f / 3.f);
            }
            u16 hi, lo; split_bf(v, hi, lo);
            Ghi[r][d] = hi; Glo[r][d] = lo;
        }
        __syncthreads();   // G ready; all A reads done
        // MFMA: A = relu(G @ W_l + b); wave w owns cols w*16..+15
        float bv = gcnB[l * HID + col];
        #pragma unroll
        for (int rt = 0; rt < 4; ++rt) {
            f32x4 acc = {0.f, 0.f, 0.f, 0.f};
            if (rt * 16 < sc) {
                short8 ah0 = *(const short8*)&Ghi[rt * 16 + lr][lg * 8];
                short8 ah1 = *(const short8*)&Ghi[rt * 16 + lr][32 + lg * 8];
                short8 al0 = *(const short8*)&Glo[rt * 16 + lr][lg * 8];
                short8 al1 = *(const short8*)&Glo[rt * 16 + lr][32 + lg * 8];
                acc = MFMA16(ah0, bh[l][0], acc);
                acc = MFMA16(ah1, bh[l][1], acc);
                acc = MFMA16(al0, bh[l][0], acc);
                acc = MFMA16(al1, bh[l][1], acc);
                acc = MFMA16(ah0, bl[l][0], acc);
                acc = MFMA16(ah1, bl[l][1], acc);
            }
            #pragma unroll
            for (int v = 0; v < 4; ++v) {
                int row = rt * 16 + lg * 4 + v;
                float val = (row < sc) ? fmaxf(acc[v] + bv, 0.f) : 0.f;
                u16 hi, lo; split_bf(val, hi, lo);
                Ahi[row][col] = hi; Alo[row][col] = lo;
            }
        }
    }
    __syncthreads();   // final hs in A; layer-3 G reads done
    // stage sW split into the dead G tile (r6 layout: G[n][k] = sW[k][n])
    #pragma unroll
    for (int t = 0; t < 16; ++t) {
        int k = w * 16 + t;
        u16 hi, lo; split_bf(sW[k * HID + d], hi, lo);
        Ghi[d][k] = hi; Glo[d][k] = lo;
    }
    // hs_red partials
    {
        float loc = 0.f;
        #pragma unroll
        for (int t = 0; t < 16; ++t) {
            int r = w + 4 * t;
            if (r < sc) loc += bf2f(Ahi[r][d]) + bf2f(Alo[r][d]);
        }
        atomicAdd(&csum[d], loc);
    }
    __syncthreads();   // sW staged; csum = per-graph hs sum
    if (tid < 64) { hs_red[(size_t)g * 64 + tid] = csum[tid]; csum[tid] = 0.f; }
    __syncthreads();
    // ys = hs @ sW (f32 out) + column stats
    {
        short8 sh0 = *(const short8*)&Ghi[col][lg * 8];
        short8 sh1 = *(const short8*)&Ghi[col][32 + lg * 8];
        short8 sl0 = *(const short8*)&Glo[col][lg * 8];
        short8 sl1 = *(const short8*)&Glo[col][32 + lg * 8];
        float ps = 0.f, pq = 0.f;
        #pragma unroll
        for (int rt = 0; rt < 4; ++rt) {
            if (rt * 16 < sc) {
                short8 ah0 = *(const short8*)&Ahi[rt * 16 + lr][lg * 8];
                short8 ah1 = *(const short8*)&Ahi[rt * 16 + lr][32 + lg * 8];
                short8 al0 = *(const short8*)&Alo[rt * 16 + lr][lg * 8];
                short8 al1 = *(const short8*)&Alo[rt * 16 + lr][32 + lg * 8];
                f32x4 acc = {0.f, 0.f, 0.f, 0.f};
                acc = MFMA16(ah0, sh0, acc);
                acc = MFMA16(ah1, sh1, acc);
                acc = MFMA16(al0, sh0, acc);
                acc = MFMA16(al1, sh1, acc);
                acc = MFMA16(ah0, sl0, acc);
                acc = MFMA16(ah1, sl1, acc);
                #pragma unroll
                for (int v = 0; v < 4; ++v) {
                    int row = rt * 16 + lg * 4 + v;
                    if (row < sc) {
                        float y = acc[v];
                        ys[(size_t)(so + row) * HID + col] = y;
                        ps += y; pq += y * y;
                    }
                }
            }
        }
        atomicAdd(&csum[col], ps);
        atomicAdd(&csq[col], pq);
    }
    __syncthreads();
    if (tid < 128)
        atomicAdd(&sumP[(size_t)(g & 63) * 128 + tid], (tid < 64) ? csum[tid] : csq[tid - 64]);
}

// ---------------- BN stats of X @ W via split-bf16 MFMA, storing Y f32 (verified r4/r6) ----------------
__global__ __launch_bounds__(256) void stats_mfma_kernel(const float* __restrict__ X,
                                                         const float* __restrict__ W, int N,
                                                         float* __restrict__ Y,
                                                         float* __restrict__ partial) {
    __shared__ __align__(16) u16 Ahi[64][LDK], Alo[64][LDK], Whi[64][LDK], Wlo[64][LDK];
    __shared__ float csum[64], csq[64];
    int tid = threadIdx.x;
    int d = tid & 63, w = tid >> 6;
    #pragma unroll
    for (int t = 0; t < 16; ++t) {
        int k = w * 16 + t;
        u16 hi, lo; split_bf(W[k * HID + d], hi, lo);
        Whi[d][k] = hi; Wlo[d][k] = lo;
    }
    if (tid < 64) { csum[tid] = 0.f; csq[tid] = 0.f; }
    __syncthreads();
    int lr = d & 15, lg = d >> 4;
    int r0 = w * 16;
    float psum[4] = {0.f, 0.f, 0.f, 0.f}, psq[4] = {0.f, 0.f, 0.f, 0.f};
    int ntiles = (N + 63) / 64;
    for (int tile = blockIdx.x; tile < ntiles; tile += gridDim.x) {
        int base = tile * 64;
        __syncthreads();
        #pragma unroll
        for (int t = 0; t < 16; ++t) {
            int r = w + 4 * t, i = base + r;
            float v = (i < N) ? X[(size_t)i * HID + d] : 0.f;
            u16 hi, lo; split_bf(v, hi, lo);
            Ahi[r][d] = hi; Alo[r][d] = lo;
        }
        __syncthreads();
        short8 ah0 = *(const short8*)&Ahi[(r0 + lr)][lg * 8];
        short8 ah1 = *(const short8*)&Ahi[(r0 + lr)][32 + lg * 8];
        short8 al0 = *(const short8*)&Alo[(r0 + lr)][lg * 8];
        short8 al1 = *(const short8*)&Alo[(r0 + lr)][32 + lg * 8];
        int rem = N - base;
        #pragma unroll
        for (int nt = 0; nt < 4; ++nt) {
            int n0 = nt * 16;
            short8 bh0 = *(const short8*)&Whi[n0 + lr][lg * 8];
            short8 bh1 = *(const short8*)&Whi[n0 + lr][32 + lg * 8];
            short8 bl0 = *(const short8*)&Wlo[n0 + lr][lg * 8];
            short8 bl1 = *(const short8*)&Wlo[n0 + lr][32 + lg * 8];
            f32x4 acc = {0.f, 0.f, 0.f, 0.f};
            acc = MFMA16(ah0, bh0, acc);
            acc = MFMA16(ah1, bh1, acc);
            acc = MFMA16(al0, bh0, acc);
            acc = MFMA16(al1, bh1, acc);
            acc = MFMA16(ah0, bl0, acc);
            acc = MFMA16(ah1, bl1, acc);
            #pragma unroll
            for (int v = 0; v < 4; ++v) {
                int r = r0 + lg * 4 + v;
                if (r < rem) {
                    psum[nt] += acc[v]; psq[nt] += acc[v] * acc[v];
                    Y[(size_t)(base + r) * HID + n0 + lr] = acc[v];
                }
            }
        }
    }
    #pragma unroll
    for (int nt = 0; nt < 4; ++nt) {
        atomicAdd(&csum[nt * 16 + lr], psum[nt]);
        atomicAdd(&csq[nt * 16 + lr], psq[nt]);
    }
    __syncthreads();
    if (tid < 64) {
        partial[(size_t)blockIdx.x * 128 + tid] = csum[tid];
        partial[(size_t)blockIdx.x * 128 + 64 + tid] = csq[tid];
    }
}

// ---------------- finalize BN affine ----------------
__global__ void finalize_kernel(const float* __restrict__ partH, int npart,
                                const float* __restrict__ sumP,
                                const float* __restrict__ gh, const float* __restrict__ bh,
                                const float* __restrict__ gs, const float* __restrict__ bs,
                                int Nm, int Ns, float* __restrict__ stats) {
    int tid = threadIdx.x;
    if (tid < 64) {
        float s = 0.f, q = 0.f;
        for (int b = 0; b < npart; ++b) { s += partH[b * 128 + tid]; q += partH[b * 128 + 64 + tid]; }
        float m = s / (float)Nm;
        float v = q / (float)Nm - m * m;
        float sc = gh[tid] * rsqrtf(v + 1e-5f);
        stats[tid] = sc;
        stats[64 + tid] = bh[tid] - m * sc;
    } else if (tid < 128) {
        int d = tid - 64;
        float s = 0.f, q = 0.f;
        for (int b = 0; b < 64; ++b) { s += sumP[b * 128 + d]; q += sumP[b * 128 + 64 + d]; }
        float m = s / (float)Ns;
        float v = q / (float)Ns - m * m;
        float sc = gs[d] * rsqrtf(v + 1e-5f);
        stats[128 + d] = sc;
        stats[192 + d] = bs[d] - m * sc;
    }
}

// ---------------- interact: affine-staged bf16 tiles + verified phase-4 MFMA (r6 verbatim) ----------------
__global__ __launch_bounds__(256) void interact_kernel(
        const float* __restrict__ h, const float* __restrict__ yh,
        const float* __restrict__ ysb, const float* __restrict__ hs_red,
        const float* __restrict__ stats,
        const int* __restrict__ moff, const int* __restrict__ mcnt,
        const int* __restrict__ soff, const int* __restrict__ scnt,
        float* __restrict__ Z) {
    __shared__ __align__(16) u16 hT[LMOL][LDK];   // _h bf16
    __shared__ __align__(16) u16 sT[LSOLV][LDK];  // _hs bf16
    __shared__ float rs[LMOL], cs[LSOLV], zz[256];
    int g = blockIdx.x, tid = threadIdx.x;
    int d = tid & 63, w = tid >> 6;
    int lr = d & 15, lg = d >> 4;
    int mo = moff[g], mc = mcnt[g], so = soff[g], sc = scnt[g];
    zz[tid] = 0.f;
    if (tid < LMOL) rs[tid] = 0.f;
    if (tid < LSOLV) cs[tid] = 0.f;
    float sch = stats[d], shh = stats[64 + d], scs = stats[128 + d], shs = stats[192 + d];
    float hsum = 0.f;
    #pragma unroll
    for (int t = 0; t < 24; ++t) {
        int m = w + 4 * t;
        float vh = 0.f, vy = 0.f;
        if (m < mc) {
            vh = h[(size_t)(mo + m) * HID + d];
            vy = yh[(size_t)(mo + m) * HID + d] * sch + shh;
        }
        hT[m][d] = f2bf(vy);
        hsum += vh;
    }
    #pragma unroll
    for (int t = 0; t < 16; ++t) {
        int n = w + 4 * t;
        float vy = 0.f;
        if (n < sc) vy = ysb[(size_t)(so + n) * HID + d] * scs + shs;
        sT[n][d] = f2bf(vy);
    }
    __syncthreads();  // B1: _h/_hs tiles ready
    atomicAdd(&zz[d], hsum);
    if (w == 0) atomicAdd(&zz[128 + d], hs_red[(size_t)g * 64 + d]);
    // phase 4 (verified r5/r6): MFMA QK^T + tanh + row/col sums
    int col = w * 16 + lr;
    if (w * 16 < sc) {
        short8 b0 = *(const short8*)&sT[col][lg * 8];
        short8 b1 = *(const short8*)&sT[col][32 + lg * 8];
        float csacc = 0.f;
        for (int mt = 0; mt < 6; ++mt) {
            if (mt * 16 >= mc) break;  // mc uniform per block
            short8 a0 = *(const short8*)&hT[mt * 16 + lr][lg * 8];
            short8 a1 = *(const short8*)&hT[mt * 16 + lr][32 + lg * 8];
            f32x4 acc = {0.f, 0.f, 0.f, 0.f};
            acc = MFMA16(a0, b0, acc);
            acc = MFMA16(a1, b1, acc);
            #pragma unroll
            for (int v = 0; v < 4; ++v) {
                float x = acc[v];
                x = fminf(fmaxf(x, -15.f), 15.f);
                float e = __expf(2.f * x);
                float t = (e - 1.f) / (e + 1.f);  // tanh; pad entries give tanh(0)=0
                csacc += t;
                float rv = t;
                rv += __shfl_xor(rv, 1); rv += __shfl_xor(rv, 2);
                rv += __shfl_xor(rv, 4); rv += __shfl_xor(rv, 8);
                if (lr == 0) atomicAdd(&rs[mt * 16 + lg * 4 + v], rv);
            }
        }
        atomicAdd(&cs[col], csacc);
    }
    __syncthreads();  // B2
    float p1 = 0.f, p3 = 0.f;
    for (int n = w; n < LSOLV; n += 4) p1 += cs[n] * bf2f(sT[n][d]);
    for (int m = w; m < LMOL; m += 4) p3 += rs[m] * bf2f(hT[m][d]);
    atomicAdd(&zz[64 + d], p1);
    atomicAdd(&zz[192 + d], p3);
    __syncthreads();  // B3
    Z[(size_t)g * 256 + tid] = zz[tid];
}

// ---------------- MLP: out = relu(z @ l1W + l1b) @ l2W + l2b ----------------
__global__ __launch_bounds__(256) void mlp_kernel(const float* __restrict__ Z,
                                                  const float* __restrict__ l1W,
                                                  const float* __restrict__ l1b,
                                                  const float* __restrict__ l2W,
                                                  const float* __restrict__ l2b,
                                                  float* __restrict__ out) {
    __shared__ float zl[16 * 256];
    __shared__ float red[64];
    int g0 = blockIdx.x * 16;
    int tid = threadIdx.x;
    for (int idx = tid; idx < 16 * 256; idx += 256) zl[idx] = Z[(size_t)g0 * 256 + idx];
    __syncthreads();
    float hid[16];
    float b = l1b[tid];
    #pragma unroll
    for (int t = 0; t < 16; ++t) hid[t] = b;
    for (int k = 0; k < 256; ++k) {
        float wv = l1W[k * 256 + tid];
        #pragma unroll
        for (int t = 0; t < 16; ++t) hid[t] += zl[t * 256 + k] * wv;
    }
    float w2 = l2W[tid];
    int lane = tid & 63, wv4 = tid >> 6;
    #pragma unroll
    for (int t = 0; t < 16; ++t) {
        float v = fmaxf(hid[t], 0.f) * w2;
        for (int off = 32; off; off >>= 1) v += __shfl_xor(v, off);
        if (lane == 0) red[wv4 * 16 + t] = v;
    }
    __syncthreads();
    if (tid < 16) out[g0 + tid] = red[tid] + red[16 + tid] + red[32 + tid] + red[48 + tid] + l2b[0];
}

extern "C" void kernel_launch(void* const* d_in, const int* in_sizes, int n_in,
                              void* d_out, int out_size, void* d_ws, size_t ws_size,
                              hipStream_t stream) {
    const float* h     = (const float*)d_in[0];
    const float* sfeat = (const float*)d_in[1];
    const float* embW  = (const float*)d_in[2];
    const float* embB  = (const float*)d_in[3];
    const float* gcnW  = (const float*)d_in[4];
    const float* gcnB  = (const float*)d_in[5];
    const float* hW    = (const float*)d_in[6];
    const float* sW    = (const float*)d_in[7];
    const float* bnhg  = (const float*)d_in[8];
    const float* bnhb  = (const float*)d_in[9];
    const float* bnsg  = (const float*)d_in[10];
    const float* bnsb  = (const float*)d_in[11];
    const float* l1W   = (const float*)d_in[12];
    const float* l1b   = (const float*)d_in[13];
    const float* l2W   = (const float*)d_in[14];
    const float* l2b   = (const float*)d_in[15];
    const int* mseg = (const int*)d_in[16];
    const int* mpos = (const int*)d_in[17];
    const int* sseg = (const int*)d_in[18];
    const int* spos = (const int*)d_in[19];

    int Nm = in_sizes[0] / HID;
    int Ns = in_sizes[1] / NODE_DIM;
    int NB = out_size;  // 4096 graphs (TGT==1)

    float* ws     = (float*)d_ws;
    float* yh     = ws;                          // [Nm][64]; prefix [Ns][64] doubles as embed out
    float* hsbuf  = ws;                          // alias (embed out, consumed before yh written)
    float* ysbuf  = yh + (size_t)Nm * HID;       // [Ns][64]
    float* hs_red = ysbuf + (size_t)Ns * HID;    // [NB][64]
    float* Z      = hs_red + (size_t)NB * 64;    // [NB][256]
    int*   moff   = (int*)(Z + (size_t)NB * 256);
    int*   soff   = moff + NB;
    int*   mcnt   = soff + NB;
    int*   scnt   = mcnt + NB;
    float* partH  = (float*)(scnt + NB);         // [NPART][128]
    float* sumP   = partH + (size_t)NPART * 128; // [64][128]
    float* statsbuf = sumP + 64 * 128;           // [256]

    hipMemsetAsync(mcnt, 0, 2 * (size_t)NB * sizeof(int), stream);
    hipMemsetAsync(sumP, 0, 64 * 128 * sizeof(float), stream);
    int nmax = Nm > Ns ? Nm : Ns;
    offsets_kernel<<<(nmax + 255) / 256, 256, 0, stream>>>(mseg, mpos, Nm, sseg, spos, Ns,
                                                           moff, soff, mcnt, scnt);
    int gblk = (Ns + 63) / 64;
    embed_mfma_kernel<<<gblk, 256, 0, stream>>>(sfeat, embW, embB, hsbuf, Ns);
    gcn_fused_kernel<<<NB, 256, 0, stream>>>(hsbuf, gcnW, gcnB, sW, soff, scnt,
                                             ysbuf, hs_red, sumP);
    stats_mfma_kernel<<<NPART, 256, 0, stream>>>(h, hW, Nm, yh, partH);
    finalize_kernel<<<1, 128, 0, stream>>>(partH, NPART, sumP,
                                           bnhg, bnhb, bnsg, bnsb, Nm, Ns, statsbuf);
    interact_kernel<<<NB, 256, 0, stream>>>(h, yh, ysbuf, hs_red, statsbuf,
                                            moff, mcnt, soff, scnt, Z);
    mlp_kernel<<<NB / 16, 256, 0, stream>>>(Z, l1W, l1b, l2W, l2b, (float*)d_out);
}

// Round 9
// 466.144 us; speedup vs baseline: 2.2805x; 1.1370x over previous
//
#include <hip/hip_runtime.h>
#include <hip/hip_bf16.h>
#include <math.h>

#define HID 64
#define NODE_DIM 74
#define LMOL 96
#define LSOLV 64
#define NPART 512
#define LDK 72      // padded LDS row stride (bf16) for K=64 tiles (144B = 9*16)
#define LDK96 104   // padded LDS row stride for K=96 tiles (208B = 13*16)
#define LDY 68      // padded LDS row stride (f32) for Y tile (272B = 17*16)

typedef __attribute__((ext_vector_type(8))) short short8;
typedef __attribute__((ext_vector_type(4))) float f32x4;
typedef unsigned short u16;
typedef unsigned int u32;

__device__ __forceinline__ u16 f2bf(float x) {
    __hip_bfloat16 b(x);              // HW RNE cvt on gfx950 (identical to integer RNE emulation)
    return *reinterpret_cast<u16*>(&b);
}
__device__ __forceinline__ float bf2f(u16 u) {
    return __uint_as_float(((u32)u) << 16);
}
__device__ __forceinline__ void split_bf(float x, u16& hi, u16& lo) {
    hi = f2bf(x);
    lo = f2bf(x - bf2f(hi));
}

#define MFMA16(a, b, c) __builtin_amdgcn_mfma_f32_16x16x32_bf16((a), (b), (c), 0, 0, 0)

// ---------------- offsets / counts ----------------
__global__ void offsets_kernel(const int* mseg, const int* mpos, int Nm,
                               const int* sseg, const int* spos, int Ns,
                               int* moff, int* soff, int* mcnt, int* scnt) {
    int i = blockIdx.x * 256 + threadIdx.x;
    if (i < Nm) {
        int s = mseg[i], p = mpos[i];
        if (p == 0) moff[s] = i;
        atomicMax(&mcnt[s], p + 1);
    }
    if (i < Ns) {
        int s = sseg[i], p = spos[i];
        if (p == 0) soff[s] = i;
        atomicMax(&scnt[s], p + 1);
    }
}

// ---------------- solvent embedding via split-bf16 MFMA (verified r4/r5/r6/r8) ----------------
__global__ __launch_bounds__(256) void embed_mfma_kernel(const float* __restrict__ feats,
                                                         const float* __restrict__ W,
                                                         const float* __restrict__ bias,
                                                         float* __restrict__ out, int Ns) {
    __shared__ __align__(16) u16 sm[4 * 64 * LDK96];  // Ahi, Alo, Whi, Wlo
    u16* Ahi = sm;
    u16* Alo = sm + 64 * LDK96;
    u16* Whi = sm + 2 * 64 * LDK96;
    u16* Wlo = sm + 3 * 64 * LDK96;
    int tid = threadIdx.x;
    int base = blockIdx.x * 64;
    {   // zero all tiles (K padded 74 -> 96)
        u32* p = (u32*)sm;
        const int tot = (4 * 64 * LDK96) / 2;
        for (int idx = tid; idx < tot; idx += 256) p[idx] = 0u;
    }
    __syncthreads();
    for (int idx = tid; idx < NODE_DIM * 64; idx += 256) {
        int k = idx >> 6, n = idx & 63;
        u16 hi, lo; split_bf(W[idx], hi, lo);
        Whi[n * LDK96 + k] = hi; Wlo[n * LDK96 + k] = lo;
    }
    int nrows = Ns - base; if (nrows > 64) nrows = 64;
    for (int idx = tid; idx < nrows * NODE_DIM; idx += 256) {
        int r = idx / NODE_DIM, c = idx - r * NODE_DIM;
        u16 hi, lo; split_bf(feats[(size_t)base * NODE_DIM + idx], hi, lo);
        Ahi[r * LDK96 + c] = hi; Alo[r * LDK96 + c] = lo;
    }
    __syncthreads();
    int lane = tid & 63, w = tid >> 6;
    int lr = lane & 15, lg = lane >> 4;
    int r0 = w * 16;
    short8 ah[3], al[3];
    #pragma unroll
    for (int kc = 0; kc < 3; ++kc) {
        ah[kc] = *(const short8*)&Ahi[(r0 + lr) * LDK96 + kc * 32 + lg * 8];
        al[kc] = *(const short8*)&Alo[(r0 + lr) * LDK96 + kc * 32 + lg * 8];
    }
    #pragma unroll
    for (int nt = 0; nt < 4; ++nt) {
        int n0 = nt * 16;
        f32x4 acc = {0.f, 0.f, 0.f, 0.f};
        #pragma unroll
        for (int kc = 0; kc < 3; ++kc) {
            short8 bh = *(const short8*)&Whi[(n0 + lr) * LDK96 + kc * 32 + lg * 8];
            short8 bl = *(const short8*)&Wlo[(n0 + lr) * LDK96 + kc * 32 + lg * 8];
            acc = MFMA16(ah[kc], bh, acc);
            acc = MFMA16(al[kc], bh, acc);
            acc = MFMA16(ah[kc], bl, acc);
        }
        float bv = bias[n0 + lr];
        int col = n0 + lr;
        #pragma unroll
        for (int v = 0; v < 4; ++v) {
            int i = base + r0 + lg * 4 + v;
            if (i < Ns) out[(size_t)i * HID + col] = acc[v] + bv;
        }
    }
}

// ---------------- fused GCN x4 (commuted: Y = A@W then ring-avg) + ys + stats + hs_red ----------------
__global__ __launch_bounds__(256, 3) void gcn_fused_kernel(
        const float* __restrict__ hs0,      // embed output [Ns][64]
        const float* __restrict__ gcnW,     // [4][64][64]
        const float* __restrict__ gcnB,     // [4][64]
        const float* __restrict__ sW,       // [64][64]
        const int* __restrict__ soff, const int* __restrict__ scnt,
        float* __restrict__ ys, float* __restrict__ hs_red,
        float* __restrict__ sumP) {
    __shared__ __align__(16) u16 Ahi[64][LDK], Alo[64][LDK];   // activations (split)
    __shared__ __align__(16) float Yt[64][LDY];                // Y = A@W (f32); later sW split (as u16)
    __shared__ float biasS[4][64];
    __shared__ float csum[64], csq[64];
    int g = blockIdx.x, tid = threadIdx.x;
    int d = tid & 63, w = tid >> 6;
    int lr = d & 15, lg = d >> 4;
    int so = soff[g], sc = scnt[g];
    int col = w * 16 + lr;
    int ar = tid >> 2, ac0 = (tid & 3) * 16;   // agg/staging ownership: row ar, cols ac0..ac0+15
    // preload split W fragments for the 4 GCN layers (B-operand, wave w owns cols w*16..+15)
    short8 bh[4][2], bl[4][2];
    #pragma unroll
    for (int l = 0; l < 4; ++l) {
        const float* W = gcnW + l * HID * HID;
        #pragma unroll
        for (int half = 0; half < 2; ++half) {
            short8 vh, vl;
            #pragma unroll
            for (int j = 0; j < 8; ++j) {
                u16 hi, lo; split_bf(W[(half * 32 + lg * 8 + j) * HID + col], hi, lo);
                vh[j] = (short)hi; vl[j] = (short)lo;
            }
            bh[l][half] = vh; bl[l][half] = vl;
        }
    }
    if (tid < 64) { csum[tid] = 0.f; csq[tid] = 0.f; }
    biasS[tid >> 6][tid & 63] = gcnB[tid];
    // stage initial hs split, vectorized (pad rows -> 0)
    if (ar < sc) {
        const float* src = hs0 + (size_t)(so + ar) * HID + ac0;
        #pragma unroll
        for (int half = 0; half < 2; ++half) {
            short8 vh, vl;
            #pragma unroll
            for (int q = 0; q < 2; ++q) {
                f32x4 v = *(const f32x4*)&src[half * 8 + q * 4];
                #pragma unroll
                for (int j = 0; j < 4; ++j) {
                    u16 hi, lo; split_bf(v[j], hi, lo);
                    vh[q * 4 + j] = (short)hi; vl[q * 4 + j] = (short)lo;
                }
            }
            *(short8*)&Ahi[ar][ac0 + half * 8] = vh;
            *(short8*)&Alo[ar][ac0 + half * 8] = vl;
        }
    } else {
        short8 vz = {0, 0, 0, 0, 0, 0, 0, 0};
        *(short8*)&Ahi[ar][ac0] = vz; *(short8*)&Ahi[ar][ac0 + 8] = vz;
        *(short8*)&Alo[ar][ac0] = vz; *(short8*)&Alo[ar][ac0 + 8] = vz;
    }
    #pragma unroll
    for (int l = 0; l < 4; ++l) {
        __syncthreads();   // A ready; previous Y reads done
        // MFMA: Y = A @ W_l  (f32 LDS; bias/relu deferred to agg)
        #pragma unroll
        for (int rt = 0; rt < 4; ++rt) {
            if (rt * 16 < sc) {
                short8 ah0 = *(const short8*)&Ahi[rt * 16 + lr][lg * 8];
                short8 ah1 = *(const short8*)&Ahi[rt * 16 + lr][32 + lg * 8];
                short8 al0 = *(const short8*)&Alo[rt * 16 + lr][lg * 8];
                short8 al1 = *(const short8*)&Alo[rt * 16 + lr][32 + lg * 8];
                f32x4 acc = {0.f, 0.f, 0.f, 0.f};
                acc = MFMA16(ah0, bh[l][0], acc);
                acc = MFMA16(ah1, bh[l][1], acc);
                acc = MFMA16(al0, bh[l][0], acc);
                acc = MFMA16(al1, bh[l][1], acc);
                acc = MFMA16(ah0, bl[l][0], acc);
                acc = MFMA16(ah1, bl[l][1], acc);
                #pragma unroll
                for (int v = 0; v < 4; ++v)
                    Yt[rt * 16 + lg * 4 + v][col] = acc[v];
            }
        }
        __syncthreads();   // Y ready; A reads done
        // agg: A = split(relu((Y[r]+Y[rp]+Y[rn])/3 + b))   [P·(A@W) == (P·A)@W]
        if (ar < sc) {
            int rp = (ar == 0) ? sc - 1 : ar - 1;
            int rn = (ar + 1 == sc) ? 0 : ar + 1;
            #pragma unroll
            for (int half = 0; half < 2; ++half) {
                short8 vh, vl;
                #pragma unroll
                for (int q = 0; q < 2; ++q) {
                    int c = ac0 + half * 8 + q * 4;
                    f32x4 y0 = *(const f32x4*)&Yt[ar][c];
                    f32x4 y1 = *(const f32x4*)&Yt[rp][c];
                    f32x4 y2 = *(const f32x4*)&Yt[rn][c];
                    #pragma unroll
                    for (int j = 0; j < 4; ++j) {
                        float v = (y0[j] + y1[j] + y2[j]) * (1.f / 3.f) + biasS[l][c + j];
                        v = fmaxf(v, 0.f);
                        u16 hi, lo; split_bf(v, hi, lo);
                        vh[q * 4 + j] = (short)hi; vl[q * 4 + j] = (short)lo;
                    }
                }
                *(short8*)&Ahi[ar][ac0 + half * 8] = vh;
                *(short8*)&Alo[ar][ac0 + half * 8] = vl;
            }
        }
        // pad rows already zero and never rewritten
    }
    __syncthreads();   // final hs in A; last Y reads done
    // stage sW split into the dead Y tile (u16 view): hi at [n*136+k], lo at [n*136+72+k]
    u16* sWu = (u16*)&Yt[0][0];
    #pragma unroll
    for (int t = 0; t < 16; ++t) {
        int k = w * 16 + t;
        u16 hi, lo; split_bf(sW[k * HID + d], hi, lo);
        sWu[d * (2 * LDY) + k] = hi;
        sWu[d * (2 * LDY) + 72 + k] = lo;
    }
    // hs_red partials
    {
        float loc = 0.f;
        #pragma unroll
        for (int t = 0; t < 16; ++t) {
            int r = w + 4 * t;
            if (r < sc) loc += bf2f(Ahi[r][d]) + bf2f(Alo[r][d]);
        }
        atomicAdd(&csum[d], loc);
    }
    __syncthreads();   // sW staged; csum = per-graph hs sum
    if (tid < 64) { hs_red[(size_t)g * 64 + tid] = csum[tid]; csum[tid] = 0.f; }
    __syncthreads();
    // ys = hs @ sW (f32 out) + column stats
    {
        short8 sh0 = *(const short8*)&sWu[col * (2 * LDY) + lg * 8];
        short8 sh1 = *(const short8*)&sWu[col * (2 * LDY) + 32 + lg * 8];
        short8 sl0 = *(const short8*)&sWu[col * (2 * LDY) + 72 + lg * 8];
        short8 sl1 = *(const short8*)&sWu[col * (2 * LDY) + 72 + 32 + lg * 8];
        float ps = 0.f, pq = 0.f;
        #pragma unroll
        for (int rt = 0; rt < 4; ++rt) {
            if (rt * 16 < sc) {
                short8 ah0 = *(const short8*)&Ahi[rt * 16 + lr][lg * 8];
                short8 ah1 = *(const short8*)&Ahi[rt * 16 + lr][32 + lg * 8];
                short8 al0 = *(const short8*)&Alo[rt * 16 + lr][lg * 8];
                short8 al1 = *(const short8*)&Alo[rt * 16 + lr][32 + lg * 8];
                f32x4 acc = {0.f, 0.f, 0.f, 0.f};
                acc = MFMA16(ah0, sh0, acc);
                acc = MFMA16(ah1, sh1, acc);
                acc = MFMA16(al0, sh0, acc);
                acc = MFMA16(al1, sh1, acc);
                acc = MFMA16(ah0, sl0, acc);
                acc = MFMA16(ah1, sl1, acc);
                #pragma unroll
                for (int v = 0; v < 4; ++v) {
                    int row = rt * 16 + lg * 4 + v;
                    if (row < sc) {
                        float y = acc[v];
                        ys[(size_t)(so + row) * HID + col] = y;
                        ps += y; pq += y * y;
                    }
                }
            }
        }
        atomicAdd(&csum[col], ps);
        atomicAdd(&csq[col], pq);
    }
    __syncthreads();
    if (tid < 128)
        atomicAdd(&sumP[(size_t)(g & 63) * 128 + tid], (tid < 64) ? csum[tid] : csq[tid - 64]);
}

// ---------------- BN stats of X @ W via split-bf16 MFMA, storing Y f32 (verified r4/r6/r8) ----------------
__global__ __launch_bounds__(256) void stats_mfma_kernel(const float* __restrict__ X,
                                                         const float* __restrict__ W, int N,
                                                         float* __restrict__ Y,
                                                         float* __restrict__ partial) {
    __shared__ __align__(16) u16 Ahi[64][LDK], Alo[64][LDK], Whi[64][LDK], Wlo[64][LDK];
    __shared__ float csum[64], csq[64];
    int tid = threadIdx.x;
    int d = tid & 63, w = tid >> 6;
    #pragma unroll
    for (int t = 0; t < 16; ++t) {
        int k = w * 16 + t;
        u16 hi, lo; split_bf(W[k * HID + d], hi, lo);
        Whi[d][k] = hi; Wlo[d][k] = lo;
    }
    if (tid < 64) { csum[tid] = 0.f; csq[tid] = 0.f; }
    __syncthreads();
    int lr = d & 15, lg = d >> 4;
    int r0 = w * 16;
    float psum[4] = {0.f, 0.f, 0.f, 0.f}, psq[4] = {0.f, 0.f, 0.f, 0.f};
    int ntiles = (N + 63) / 64;
    for (int tile = blockIdx.x; tile < ntiles; tile += gridDim.x) {
        int base = tile * 64;
        __syncthreads();
        #pragma unroll
        for (int t = 0; t < 16; ++t) {
            int r = w + 4 * t, i = base + r;
            float v = (i < N) ? X[(size_t)i * HID + d] : 0.f;
            u16 hi, lo; split_bf(v, hi, lo);
            Ahi[r][d] = hi; Alo[r][d] = lo;
        }
        __syncthreads();
        short8 ah0 = *(const short8*)&Ahi[(r0 + lr)][lg * 8];
        short8 ah1 = *(const short8*)&Ahi[(r0 + lr)][32 + lg * 8];
        short8 al0 = *(const short8*)&Alo[(r0 + lr)][lg * 8];
        short8 al1 = *(const short8*)&Alo[(r0 + lr)][32 + lg * 8];
        int rem = N - base;
        #pragma unroll
        for (int nt = 0; nt < 4; ++nt) {
            int n0 = nt * 16;
            short8 bh0 = *(const short8*)&Whi[n0 + lr][lg * 8];
            short8 bh1 = *(const short8*)&Whi[n0 + lr][32 + lg * 8];
            short8 bl0 = *(const short8*)&Wlo[n0 + lr][lg * 8];
            short8 bl1 = *(const short8*)&Wlo[n0 + lr][32 + lg * 8];
            f32x4 acc = {0.f, 0.f, 0.f, 0.f};
            acc = MFMA16(ah0, bh0, acc);
            acc = MFMA16(ah1, bh1, acc);
            acc = MFMA16(al0, bh0, acc);
            acc = MFMA16(al1, bh1, acc);
            acc = MFMA16(ah0, bl0, acc);
            acc = MFMA16(ah1, bl1, acc);
            #pragma unroll
            for (int v = 0; v < 4; ++v) {
                int r = r0 + lg * 4 + v;
                if (r < rem) {
                    psum[nt] += acc[v]; psq[nt] += acc[v] * acc[v];
                    Y[(size_t)(base + r) * HID + n0 + lr] = acc[v];
                }
            }
        }
    }
    #pragma unroll
    for (int nt = 0; nt < 4; ++nt) {
        atomicAdd(&csum[nt * 16 + lr], psum[nt]);
        atomicAdd(&csq[nt * 16 + lr], psq[nt]);
    }
    __syncthreads();
    if (tid < 64) {
        partial[(size_t)blockIdx.x * 128 + tid] = csum[tid];
        partial[(size_t)blockIdx.x * 128 + 64 + tid] = csq[tid];
    }
}

// ---------------- finalize BN affine ----------------
__global__ void finalize_kernel(const float* __restrict__ partH, int npart,
                                const float* __restrict__ sumP,
                                const float* __restrict__ gh, const float* __restrict__ bh,
                                const float* __restrict__ gs, const float* __restrict__ bs,
                                int Nm, int Ns, float* __restrict__ stats) {
    int tid = threadIdx.x;
    if (tid < 64) {
        float s = 0.f, q = 0.f;
        for (int b = 0; b < npart; ++b) { s += partH[b * 128 + tid]; q += partH[b * 128 + 64 + tid]; }
        float m = s / (float)Nm;
        float v = q / (float)Nm - m * m;
        float sc = gh[tid] * rsqrtf(v + 1e-5f);
        stats[tid] = sc;
        stats[64 + tid] = bh[tid] - m * sc;
    } else if (tid < 128) {
        int d = tid - 64;
        float s = 0.f, q = 0.f;
        for (int b = 0; b < 64; ++b) { s += sumP[b * 128 + d]; q += sumP[b * 128 + 64 + d]; }
        float m = s / (float)Ns;
        float v = q / (float)Ns - m * m;
        float sc = gs[d] * rsqrtf(v + 1e-5f);
        stats[128 + d] = sc;
        stats[192 + d] = bs[d] - m * sc;
    }
}

// ---------------- interact: affine-staged bf16 tiles + verified phase-4 MFMA (r6/r8 verbatim) ----------------
__global__ __launch_bounds__(256) void interact_kernel(
        const float* __restrict__ h, const float* __restrict__ yh,
        const float* __restrict__ ysb, const float* __restrict__ hs_red,
        const float* __restrict__ stats,
        const int* __restrict__ moff, const int* __restrict__ mcnt,
        const int* __restrict__ soff, const int* __restrict__ scnt,
        float* __restrict__ Z) {
    __shared__ __align__(16) u16 hT[LMOL][LDK];   // _h bf16
    __shared__ __align__(16) u16 sT[LSOLV][LDK];  // _hs bf16
    __shared__ float rs[LMOL], cs[LSOLV], zz[256];
    int g = blockIdx.x, tid = threadIdx.x;
    int d = tid & 63, w = tid >> 6;
    int lr = d & 15, lg = d >> 4;
    int mo = moff[g], mc = mcnt[g], so = soff[g], sc = scnt[g];
    zz[tid] = 0.f;
    if (tid < LMOL) rs[tid] = 0.f;
    if (tid < LSOLV) cs[tid] = 0.f;
    float sch = stats[d], shh = stats[64 + d], scs = stats[128 + d], shs = stats[192 + d];
    float hsum = 0.f;
    #pragma unroll
    for (int t = 0; t < 24; ++t) {
        int m = w + 4 * t;
        float vh = 0.f, vy = 0.f;
        if (m < mc) {
            vh = h[(size_t)(mo + m) * HID + d];
            vy = yh[(size_t)(mo + m) * HID + d] * sch + shh;
        }
        hT[m][d] = f2bf(vy);
        hsum += vh;
    }
    #pragma unroll
    for (int t = 0; t < 16; ++t) {
        int n = w + 4 * t;
        float vy = 0.f;
        if (n < sc) vy = ysb[(size_t)(so + n) * HID + d] * scs + shs;
        sT[n][d] = f2bf(vy);
    }
    __syncthreads();  // B1: _h/_hs tiles ready
    atomicAdd(&zz[d], hsum);
    if (w == 0) atomicAdd(&zz[128 + d], hs_red[(size_t)g * 64 + d]);
    // phase 4 (verified r5/r6/r8): MFMA QK^T + tanh + row/col sums
    int col = w * 16 + lr;
    if (w * 16 < sc) {
        short8 b0 = *(const short8*)&sT[col][lg * 8];
        short8 b1 = *(const short8*)&sT[col][32 + lg * 8];
        float csacc = 0.f;
        for (int mt = 0; mt < 6; ++mt) {
            if (mt * 16 >= mc) break;  // mc uniform per block
            short8 a0 = *(const short8*)&hT[mt * 16 + lr][lg * 8];
            short8 a1 = *(const short8*)&hT[mt * 16 + lr][32 + lg * 8];
            f32x4 acc = {0.f, 0.f, 0.f, 0.f};
            acc = MFMA16(a0, b0, acc);
            acc = MFMA16(a1, b1, acc);
            #pragma unroll
            for (int v = 0; v < 4; ++v) {
                float x = acc[v];
                x = fminf(fmaxf(x, -15.f), 15.f);
                float e = __expf(2.f * x);
                float t = (e - 1.f) / (e + 1.f);  // tanh; pad entries give tanh(0)=0
                csacc += t;
                float rv = t;
                rv += __shfl_xor(rv, 1); rv += __shfl_xor(rv, 2);
                rv += __shfl_xor(rv, 4); rv += __shfl_xor(rv, 8);
                if (lr == 0) atomicAdd(&rs[mt * 16 + lg * 4 + v], rv);
            }
        }
        atomicAdd(&cs[col], csacc);
    }
    __syncthreads();  // B2
    float p1 = 0.f, p3 = 0.f;
    for (int n = w; n < LSOLV; n += 4) p1 += cs[n] * bf2f(sT[n][d]);
    for (int m = w; m < LMOL; m += 4) p3 += rs[m] * bf2f(hT[m][d]);
    atomicAdd(&zz[64 + d], p1);
    atomicAdd(&zz[192 + d], p3);
    __syncthreads();  // B3
    Z[(size_t)g * 256 + tid] = zz[tid];
}

// ---------------- MLP: out = relu(z @ l1W + l1b) @ l2W + l2b ----------------
__global__ __launch_bounds__(256) void mlp_kernel(const float* __restrict__ Z,
                                                  const float* __restrict__ l1W,
                                                  const float* __restrict__ l1b,
                                                  const float* __restrict__ l2W,
                                                  const float* __restrict__ l2b,
                                                  float* __restrict__ out) {
    __shared__ float zl[16 * 256];
    __shared__ float red[64];
    int g0 = blockIdx.x * 16;
    int tid = threadIdx.x;
    for (int idx = tid; idx < 16 * 256; idx += 256) zl[idx] = Z[(size_t)g0 * 256 + idx];
    __syncthreads();
    float hid[16];
    float b = l1b[tid];
    #pragma unroll
    for (int t = 0; t < 16; ++t) hid[t] = b;
    for (int k = 0; k < 256; ++k) {
        float wv = l1W[k * 256 + tid];
        #pragma unroll
        for (int t = 0; t < 16; ++t) hid[t] += zl[t * 256 + k] * wv;
    }
    float w2 = l2W[tid];
    int lane = tid & 63, wv4 = tid >> 6;
    #pragma unroll
    for (int t = 0; t < 16; ++t) {
        float v = fmaxf(hid[t], 0.f) * w2;
        for (int off = 32; off; off >>= 1) v += __shfl_xor(v, off);
        if (lane == 0) red[wv4 * 16 + t] = v;
    }
    __syncthreads();
    if (tid < 16) out[g0 + tid] = red[tid] + red[16 + tid] + red[32 + tid] + red[48 + tid] + l2b[0];
}

extern "C" void kernel_launch(void* const* d_in, const int* in_sizes, int n_in,
                              void* d_out, int out_size, void* d_ws, size_t ws_size,
                              hipStream_t stream) {
    const float* h     = (const float*)d_in[0];
    const float* sfeat = (const float*)d_in[1];
    const float* embW  = (const float*)d_in[2];
    const float* embB  = (const float*)d_in[3];
    const float* gcnW  = (const float*)d_in[4];
    const float* gcnB  = (const float*)d_in[5];
    const float* hW    = (const float*)d_in[6];
    const float* sW    = (const float*)d_in[7];
    const float* bnhg  = (const float*)d_in[8];
    const float* bnhb  = (const float*)d_in[9];
    const float* bnsg  = (const float*)d_in[10];
    const float* bnsb  = (const float*)d_in[11];
    const float* l1W   = (const float*)d_in[12];
    const float* l1b   = (const float*)d_in[13];
    const float* l2W   = (const float*)d_in[14];
    const float* l2b   = (const float*)d_in[15];
    const int* mseg = (const int*)d_in[16];
    const int* mpos = (const int*)d_in[17];
    const int* sseg = (const int*)d_in[18];
    const int* spos = (const int*)d_in[19];

    int Nm = in_sizes[0] / HID;
    int Ns = in_sizes[1] / NODE_DIM;
    int NB = out_size;  // 4096 graphs (TGT==1)

    float* ws     = (float*)d_ws;
    float* yh     = ws;                          // [Nm][64]; prefix [Ns][64] doubles as embed out
    float* hsbuf  = ws;                          // alias (embed out, consumed before yh written)
    float* ysbuf  = yh + (size_t)Nm * HID;       // [Ns][64]
    float* hs_red = ysbuf + (size_t)Ns * HID;    // [NB][64]
    float* Z      = hs_red + (size_t)NB * 64;    // [NB][256]
    int*   moff   = (int*)(Z + (size_t)NB * 256);
    int*   soff   = moff + NB;
    int*   mcnt   = soff + NB;
    int*   scnt   = mcnt + NB;
    float* partH  = (float*)(scnt + NB);         // [NPART][128]
    float* sumP   = partH + (size_t)NPART * 128; // [64][128]
    float* statsbuf = sumP + 64 * 128;           // [256]

    hipMemsetAsync(mcnt, 0, 2 * (size_t)NB * sizeof(int), stream);
    hipMemsetAsync(sumP, 0, 64 * 128 * sizeof(float), stream);
    int nmax = Nm > Ns ? Nm : Ns;
    offsets_kernel<<<(nmax + 255) / 256, 256, 0, stream>>>(mseg, mpos, Nm, sseg, spos, Ns,
                                                           moff, soff, mcnt, scnt);
    int gblk = (Ns + 63) / 64;
    embed_mfma_kernel<<<gblk, 256, 0, stream>>>(sfeat, embW, embB, hsbuf, Ns);
    gcn_fused_kernel<<<NB, 256, 0, stream>>>(hsbuf, gcnW, gcnB, sW, soff, scnt,
                                             ysbuf, hs_red, sumP);
    stats_mfma_kernel<<<NPART, 256, 0, stream>>>(h, hW, Nm, yh, partH);
    finalize_kernel<<<1, 128, 0, stream>>>(partH, NPART, sumP,
                                           bnhg, bnhb, bnsg, bnsb, Nm, Ns, statsbuf);
    interact_kernel<<<NB, 256, 0, stream>>>(h, yh, ysbuf, hs_red, statsbuf,
                                            moff, mcnt, soff, scnt, Z);
    mlp_kernel<<<NB / 16, 256, 0, stream>>>(Z, l1W, l1b, l2W, l2b, (float*)d_out);
}

// Round 10
// 362.135 us; speedup vs baseline: 2.9355x; 1.2872x over previous
//
#include <hip/hip_runtime.h>
#include <hip/hip_bf16.h>
#include <math.h>

#define HID 64
#define NODE_DIM 74
#define LMOL 96
#define LSOLV 64
#define NPART 512
#define LDK 72      // padded LDS row stride (bf16) for K=64 tiles (144B = 9*16)
#define LDK96 104   // padded LDS row stride for K=96 tiles (208B = 13*16)
#define LDY 68      // padded LDS row stride (f32) for Y tile (272B = 17*16)

typedef __attribute__((ext_vector_type(8))) short short8;
typedef __attribute__((ext_vector_type(4))) float f32x4;
typedef unsigned short u16;
typedef unsigned int u32;

__device__ __forceinline__ u16 f2bf(float x) {
    __hip_bfloat16 b(x);              // HW RNE cvt on gfx950
    return *reinterpret_cast<u16*>(&b);
}
__device__ __forceinline__ float bf2f(u16 u) {
    return __uint_as_float(((u32)u) << 16);
}
__device__ __forceinline__ void split_bf(float x, u16& hi, u16& lo) {
    hi = f2bf(x);
    lo = f2bf(x - bf2f(hi));
}

#define MFMA16(a, b, c) __builtin_amdgcn_mfma_f32_16x16x32_bf16((a), (b), (c), 0, 0, 0)

// ---------------- offsets / counts ----------------
__global__ void offsets_kernel(const int* mseg, const int* mpos, int Nm,
                               const int* sseg, const int* spos, int Ns,
                               int* moff, int* soff, int* mcnt, int* scnt) {
    int i = blockIdx.x * 256 + threadIdx.x;
    if (i < Nm) {
        int s = mseg[i], p = mpos[i];
        if (p == 0) moff[s] = i;
        atomicMax(&mcnt[s], p + 1);
    }
    if (i < Ns) {
        int s = sseg[i], p = spos[i];
        if (p == 0) soff[s] = i;
        atomicMax(&scnt[s], p + 1);
    }
}

// ---------------- solvent embedding via split-bf16 MFMA (verified r4/r5/r6/r8/r9) ----------------
__global__ __launch_bounds__(256) void embed_mfma_kernel(const float* __restrict__ feats,
                                                         const float* __restrict__ W,
                                                         const float* __restrict__ bias,
                                                         float* __restrict__ out, int Ns) {
    __shared__ __align__(16) u16 sm[4 * 64 * LDK96];  // Ahi, Alo, Whi, Wlo
    u16* Ahi = sm;
    u16* Alo = sm + 64 * LDK96;
    u16* Whi = sm + 2 * 64 * LDK96;
    u16* Wlo = sm + 3 * 64 * LDK96;
    int tid = threadIdx.x;
    int base = blockIdx.x * 64;
    {   // zero all tiles (K padded 74 -> 96)
        u32* p = (u32*)sm;
        const int tot = (4 * 64 * LDK96) / 2;
        for (int idx = tid; idx < tot; idx += 256) p[idx] = 0u;
    }
    __syncthreads();
    for (int idx = tid; idx < NODE_DIM * 64; idx += 256) {
        int k = idx >> 6, n = idx & 63;
        u16 hi, lo; split_bf(W[idx], hi, lo);
        Whi[n * LDK96 + k] = hi; Wlo[n * LDK96 + k] = lo;
    }
    int nrows = Ns - base; if (nrows > 64) nrows = 64;
    for (int idx = tid; idx < nrows * NODE_DIM; idx += 256) {
        int r = idx / NODE_DIM, c = idx - r * NODE_DIM;
        u16 hi, lo; split_bf(feats[(size_t)base * NODE_DIM + idx], hi, lo);
        Ahi[r * LDK96 + c] = hi; Alo[r * LDK96 + c] = lo;
    }
    __syncthreads();
    int lane = tid & 63, w = tid >> 6;
    int lr = lane & 15, lg = lane >> 4;
    int r0 = w * 16;
    short8 ah[3], al[3];
    #pragma unroll
    for (int kc = 0; kc < 3; ++kc) {
        ah[kc] = *(const short8*)&Ahi[(r0 + lr) * LDK96 + kc * 32 + lg * 8];
        al[kc] = *(const short8*)&Alo[(r0 + lr) * LDK96 + kc * 32 + lg * 8];
    }
    #pragma unroll
    for (int nt = 0; nt < 4; ++nt) {
        int n0 = nt * 16;
        f32x4 acc = {0.f, 0.f, 0.f, 0.f};
        #pragma unroll
        for (int kc = 0; kc < 3; ++kc) {
            short8 bh = *(const short8*)&Whi[(n0 + lr) * LDK96 + kc * 32 + lg * 8];
            short8 bl = *(const short8*)&Wlo[(n0 + lr) * LDK96 + kc * 32 + lg * 8];
            acc = MFMA16(ah[kc], bh, acc);
            acc = MFMA16(al[kc], bh, acc);
            acc = MFMA16(ah[kc], bl, acc);
        }
        float bv = bias[n0 + lr];
        int col = n0 + lr;
        #pragma unroll
        for (int v = 0; v < 4; ++v) {
            int i = base + r0 + lg * 4 + v;
            if (i < Ns) out[(size_t)i * HID + col] = acc[v] + bv;
        }
    }
}

// ---------------- fused GCN x4 (commuted: Y = A@W then ring-avg) + ys + stats + hs_red (r9) ----------------
__global__ __launch_bounds__(256, 3) void gcn_fused_kernel(
        const float* __restrict__ hs0,      // embed output [Ns][64]
        const float* __restrict__ gcnW,     // [4][64][64]
        const float* __restrict__ gcnB,     // [4][64]
        const float* __restrict__ sW,       // [64][64]
        const int* __restrict__ soff, const int* __restrict__ scnt,
        float* __restrict__ ys, float* __restrict__ hs_red,
        float* __restrict__ sumP) {
    __shared__ __align__(16) u16 Ahi[64][LDK], Alo[64][LDK];   // activations (split)
    __shared__ __align__(16) float Yt[64][LDY];                // Y = A@W (f32); later sW split (as u16)
    __shared__ float biasS[4][64];
    __shared__ float csum[64], csq[64];
    int g = blockIdx.x, tid = threadIdx.x;
    int d = tid & 63, w = tid >> 6;
    int lr = d & 15, lg = d >> 4;
    int so = soff[g], sc = scnt[g];
    int col = w * 16 + lr;
    int ar = tid >> 2, ac0 = (tid & 3) * 16;   // agg/staging ownership: row ar, cols ac0..ac0+15
    // preload split W fragments for the 4 GCN layers (B-operand, wave w owns cols w*16..+15)
    short8 bh[4][2], bl[4][2];
    #pragma unroll
    for (int l = 0; l < 4; ++l) {
        const float* W = gcnW + l * HID * HID;
        #pragma unroll
        for (int half = 0; half < 2; ++half) {
            short8 vh, vl;
            #pragma unroll
            for (int j = 0; j < 8; ++j) {
                u16 hi, lo; split_bf(W[(half * 32 + lg * 8 + j) * HID + col], hi, lo);
                vh[j] = (short)hi; vl[j] = (short)lo;
            }
            bh[l][half] = vh; bl[l][half] = vl;
        }
    }
    if (tid < 64) { csum[tid] = 0.f; csq[tid] = 0.f; }
    biasS[tid >> 6][tid & 63] = gcnB[tid];
    // stage initial hs split, vectorized (pad rows -> 0)
    if (ar < sc) {
        const float* src = hs0 + (size_t)(so + ar) * HID + ac0;
        #pragma unroll
        for (int half = 0; half < 2; ++half) {
            short8 vh, vl;
            #pragma unroll
            for (int q = 0; q < 2; ++q) {
                f32x4 v = *(const f32x4*)&src[half * 8 + q * 4];
                #pragma unroll
                for (int j = 0; j < 4; ++j) {
                    u16 hi, lo; split_bf(v[j], hi, lo);
                    vh[q * 4 + j] = (short)hi; vl[q * 4 + j] = (short)lo;
                }
            }
            *(short8*)&Ahi[ar][ac0 + half * 8] = vh;
            *(short8*)&Alo[ar][ac0 + half * 8] = vl;
        }
    } else {
        short8 vz = {0, 0, 0, 0, 0, 0, 0, 0};
        *(short8*)&Ahi[ar][ac0] = vz; *(short8*)&Ahi[ar][ac0 + 8] = vz;
        *(short8*)&Alo[ar][ac0] = vz; *(short8*)&Alo[ar][ac0 + 8] = vz;
    }
    #pragma unroll
    for (int l = 0; l < 4; ++l) {
        __syncthreads();   // A ready; previous Y reads done
        // MFMA: Y = A @ W_l  (f32 LDS; bias/relu deferred to agg)
        #pragma unroll
        for (int rt = 0; rt < 4; ++rt) {
            if (rt * 16 < sc) {
                short8 ah0 = *(const short8*)&Ahi[rt * 16 + lr][lg * 8];
                short8 ah1 = *(const short8*)&Ahi[rt * 16 + lr][32 + lg * 8];
                short8 al0 = *(const short8*)&Alo[rt * 16 + lr][lg * 8];
                short8 al1 = *(const short8*)&Alo[rt * 16 + lr][32 + lg * 8];
                f32x4 acc = {0.f, 0.f, 0.f, 0.f};
                acc = MFMA16(ah0, bh[l][0], acc);
                acc = MFMA16(ah1, bh[l][1], acc);
                acc = MFMA16(al0, bh[l][0], acc);
                acc = MFMA16(al1, bh[l][1], acc);
                acc = MFMA16(ah0, bl[l][0], acc);
                acc = MFMA16(ah1, bl[l][1], acc);
                #pragma unroll
                for (int v = 0; v < 4; ++v)
                    Yt[rt * 16 + lg * 4 + v][col] = acc[v];
            }
        }
        __syncthreads();   // Y ready; A reads done
        // agg: A = split(relu((Y[r]+Y[rp]+Y[rn])/3 + b))   [P·(A@W) == (P·A)@W]
        if (ar < sc) {
            int rp = (ar == 0) ? sc - 1 : ar - 1;
            int rn = (ar + 1 == sc) ? 0 : ar + 1;
            #pragma unroll
            for (int half = 0; half < 2; ++half) {
                short8 vh, vl;
                #pragma unroll
                for (int q = 0; q < 2; ++q) {
                    int c = ac0 + half * 8 + q * 4;
                    f32x4 y0 = *(const f32x4*)&Yt[ar][c];
                    f32x4 y1 = *(const f32x4*)&Yt[rp][c];
                    f32x4 y2 = *(const f32x4*)&Yt[rn][c];
                    #pragma unroll
                    for (int j = 0; j < 4; ++j) {
                        float v = (y0[j] + y1[j] + y2[j]) * (1.f / 3.f) + biasS[l][c + j];
                        v = fmaxf(v, 0.f);
                        u16 hi, lo; split_bf(v, hi, lo);
                        vh[q * 4 + j] = (short)hi; vl[q * 4 + j] = (short)lo;
                    }
                }
                *(short8*)&Ahi[ar][ac0 + half * 8] = vh;
                *(short8*)&Alo[ar][ac0 + half * 8] = vl;
            }
        }
        // pad rows already zero and never rewritten
    }
    __syncthreads();   // final hs in A; last Y reads done
    // stage sW split into the dead Y tile (u16 view)
    u16* sWu = (u16*)&Yt[0][0];
    #pragma unroll
    for (int t = 0; t < 16; ++t) {
        int k = w * 16 + t;
        u16 hi, lo; split_bf(sW[k * HID + d], hi, lo);
        sWu[d * (2 * LDY) + k] = hi;
        sWu[d * (2 * LDY) + 72 + k] = lo;
    }
    // hs_red partials
    {
        float loc = 0.f;
        #pragma unroll
        for (int t = 0; t < 16; ++t) {
            int r = w + 4 * t;
            if (r < sc) loc += bf2f(Ahi[r][d]) + bf2f(Alo[r][d]);
        }
        atomicAdd(&csum[d], loc);
    }
    __syncthreads();   // sW staged; csum = per-graph hs sum
    if (tid < 64) { hs_red[(size_t)g * 64 + tid] = csum[tid]; csum[tid] = 0.f; }
    __syncthreads();
    // ys = hs @ sW (f32 out) + column stats
    {
        short8 sh0 = *(const short8*)&sWu[col * (2 * LDY) + lg * 8];
        short8 sh1 = *(const short8*)&sWu[col * (2 * LDY) + 32 + lg * 8];
        short8 sl0 = *(const short8*)&sWu[col * (2 * LDY) + 72 + lg * 8];
        short8 sl1 = *(const short8*)&sWu[col * (2 * LDY) + 72 + 32 + lg * 8];
        float ps = 0.f, pq = 0.f;
        #pragma unroll
        for (int rt = 0; rt < 4; ++rt) {
            if (rt * 16 < sc) {
                short8 ah0 = *(const short8*)&Ahi[rt * 16 + lr][lg * 8];
                short8 ah1 = *(const short8*)&Ahi[rt * 16 + lr][32 + lg * 8];
                short8 al0 = *(const short8*)&Alo[rt * 16 + lr][lg * 8];
                short8 al1 = *(const short8*)&Alo[rt * 16 + lr][32 + lg * 8];
                f32x4 acc = {0.f, 0.f, 0.f, 0.f};
                acc = MFMA16(ah0, sh0, acc);
                acc = MFMA16(ah1, sh1, acc);
                acc = MFMA16(al0, sh0, acc);
                acc = MFMA16(al1, sh1, acc);
                acc = MFMA16(ah0, sl0, acc);
                acc = MFMA16(ah1, sl1, acc);
                #pragma unroll
                for (int v = 0; v < 4; ++v) {
                    int row = rt * 16 + lg * 4 + v;
                    if (row < sc) {
                        float y = acc[v];
                        ys[(size_t)(so + row) * HID + col] = y;
                        ps += y; pq += y * y;
                    }
                }
            }
        }
        atomicAdd(&csum[col], ps);
        atomicAdd(&csq[col], pq);
    }
    __syncthreads();
    if (tid < 128)
        atomicAdd(&sumP[(size_t)(g & 63) * 128 + tid], (tid < 64) ? csum[tid] : csq[tid - 64]);
}

// ---------------- BN stats of X @ W via split-bf16 MFMA, storing Y f32 (verified r4/r6/r8/r9) ----------------
__global__ __launch_bounds__(256) void stats_mfma_kernel(const float* __restrict__ X,
                                                         const float* __restrict__ W, int N,
                                                         float* __restrict__ Y,
                                                         float* __restrict__ partial) {
    __shared__ __align__(16) u16 Ahi[64][LDK], Alo[64][LDK], Whi[64][LDK], Wlo[64][LDK];
    __shared__ float csum[64], csq[64];
    int tid = threadIdx.x;
    int d = tid & 63, w = tid >> 6;
    #pragma unroll
    for (int t = 0; t < 16; ++t) {
        int k = w * 16 + t;
        u16 hi, lo; split_bf(W[k * HID + d], hi, lo);
        Whi[d][k] = hi; Wlo[d][k] = lo;
    }
    if (tid < 64) { csum[tid] = 0.f; csq[tid] = 0.f; }
    __syncthreads();
    int lr = d & 15, lg = d >> 4;
    int r0 = w * 16;
    float psum[4] = {0.f, 0.f, 0.f, 0.f}, psq[4] = {0.f, 0.f, 0.f, 0.f};
    int ntiles = (N + 63) / 64;
    for (int tile = blockIdx.x; tile < ntiles; tile += gridDim.x) {
        int base = tile * 64;
        __syncthreads();
        #pragma unroll
        for (int t = 0; t < 16; ++t) {
            int r = w + 4 * t, i = base + r;
            float v = (i < N) ? X[(size_t)i * HID + d] : 0.f;
            u16 hi, lo; split_bf(v, hi, lo);
            Ahi[r][d] = hi; Alo[r][d] = lo;
        }
        __syncthreads();
        short8 ah0 = *(const short8*)&Ahi[(r0 + lr)][lg * 8];
        short8 ah1 = *(const short8*)&Ahi[(r0 + lr)][32 + lg * 8];
        short8 al0 = *(const short8*)&Alo[(r0 + lr)][lg * 8];
        short8 al1 = *(const short8*)&Alo[(r0 + lr)][32 + lg * 8];
        int rem = N - base;
        #pragma unroll
        for (int nt = 0; nt < 4; ++nt) {
            int n0 = nt * 16;
            short8 bh0 = *(const short8*)&Whi[n0 + lr][lg * 8];
            short8 bh1 = *(const short8*)&Whi[n0 + lr][32 + lg * 8];
            short8 bl0 = *(const short8*)&Wlo[n0 + lr][lg * 8];
            short8 bl1 = *(const short8*)&Wlo[n0 + lr][32 + lg * 8];
            f32x4 acc = {0.f, 0.f, 0.f, 0.f};
            acc = MFMA16(ah0, bh0, acc);
            acc = MFMA16(ah1, bh1, acc);
            acc = MFMA16(al0, bh0, acc);
            acc = MFMA16(al1, bh1, acc);
            acc = MFMA16(ah0, bl0, acc);
            acc = MFMA16(ah1, bl1, acc);
            #pragma unroll
            for (int v = 0; v < 4; ++v) {
                int r = r0 + lg * 4 + v;
                if (r < rem) {
                    psum[nt] += acc[v]; psq[nt] += acc[v] * acc[v];
                    Y[(size_t)(base + r) * HID + n0 + lr] = acc[v];
                }
            }
        }
    }
    #pragma unroll
    for (int nt = 0; nt < 4; ++nt) {
        atomicAdd(&csum[nt * 16 + lr], psum[nt]);
        atomicAdd(&csq[nt * 16 + lr], psq[nt]);
    }
    __syncthreads();
    if (tid < 64) {
        partial[(size_t)blockIdx.x * 128 + tid] = csum[tid];
        partial[(size_t)blockIdx.x * 128 + 64 + tid] = csq[tid];
    }
}

// ---------------- finalize BN affine: 8-way parallel reduction (1024 threads) ----------------
__global__ __launch_bounds__(1024) void finalize_kernel(const float* __restrict__ partH, int npart,
                                const float* __restrict__ sumP,
                                const float* __restrict__ gh, const float* __restrict__ bh,
                                const float* __restrict__ gs, const float* __restrict__ bs,
                                int Nm, int Ns, float* __restrict__ stats) {
    __shared__ float redS[1024], redQ[1024];
    int tid = threadIdx.x;
    int out = tid & 127;   // output column slot: 0..63 = h path, 64..127 = solvent path
    int j = tid >> 7;      // 0..7 reduction lane
    float s = 0.f, q = 0.f;
    if (out < 64) {
        for (int b = j; b < npart; b += 8) {
            s += partH[b * 128 + out];
            q += partH[b * 128 + 64 + out];
        }
    } else {
        int d = out - 64;
        for (int b = j; b < 64; b += 8) {
            s += sumP[b * 128 + d];
            q += sumP[b * 128 + 64 + d];
        }
    }
    redS[tid] = s; redQ[tid] = q;
    __syncthreads();
    if (tid < 128) {
        float ts = 0.f, tq = 0.f;
        #pragma unroll
        for (int jj = 0; jj < 8; ++jj) { ts += redS[jj * 128 + tid]; tq += redQ[jj * 128 + tid]; }
        if (tid < 64) {
            float m = ts / (float)Nm;
            float v = tq / (float)Nm - m * m;
            float sc = gh[tid] * rsqrtf(v + 1e-5f);
            stats[tid] = sc;
            stats[64 + tid] = bh[tid] - m * sc;
        } else {
            int d = tid - 64;
            float m = ts / (float)Ns;
            float v = tq / (float)Ns - m * m;
            float sc = gs[d] * rsqrtf(v + 1e-5f);
            stats[128 + d] = sc;
            stats[192 + d] = bs[d] - m * sc;
        }
    }
}

// ---------------- interact: affine-staged bf16 tiles + verified phase-4 MFMA (r6/r8/r9 verbatim) ----------------
__global__ __launch_bounds__(256) void interact_kernel(
        const float* __restrict__ h, const float* __restrict__ yh,
        const float* __restrict__ ysb, const float* __restrict__ hs_red,
        const float* __restrict__ stats,
        const int* __restrict__ moff, const int* __restrict__ mcnt,
        const int* __restrict__ soff, const int* __restrict__ scnt,
        float* __restrict__ Z) {
    __shared__ __align__(16) u16 hT[LMOL][LDK];   // _h bf16
    __shared__ __align__(16) u16 sT[LSOLV][LDK];  // _hs bf16
    __shared__ float rs[LMOL], cs[LSOLV], zz[256];
    int g = blockIdx.x, tid = threadIdx.x;
    int d = tid & 63, w = tid >> 6;
    int lr = d & 15, lg = d >> 4;
    int mo = moff[g], mc = mcnt[g], so = soff[g], sc = scnt[g];
    zz[tid] = 0.f;
    if (tid < LMOL) rs[tid] = 0.f;
    if (tid < LSOLV) cs[tid] = 0.f;
    float sch = stats[d], shh = stats[64 + d], scs = stats[128 + d], shs = stats[192 + d];
    float hsum = 0.f;
    #pragma unroll
    for (int t = 0; t < 24; ++t) {
        int m = w + 4 * t;
        float vh = 0.f, vy = 0.f;
        if (m < mc) {
            vh = h[(size_t)(mo + m) * HID + d];
            vy = yh[(size_t)(mo + m) * HID + d] * sch + shh;
        }
        hT[m][d] = f2bf(vy);
        hsum += vh;
    }
    #pragma unroll
    for (int t = 0; t < 16; ++t) {
        int n = w + 4 * t;
        float vy = 0.f;
        if (n < sc) vy = ysb[(size_t)(so + n) * HID + d] * scs + shs;
        sT[n][d] = f2bf(vy);
    }
    __syncthreads();  // B1: _h/_hs tiles ready
    atomicAdd(&zz[d], hsum);
    if (w == 0) atomicAdd(&zz[128 + d], hs_red[(size_t)g * 64 + d]);
    // phase 4 (verified r5/r6/r8/r9): MFMA QK^T + tanh + row/col sums
    int col = w * 16 + lr;
    if (w * 16 < sc) {
        short8 b0 = *(const short8*)&sT[col][lg * 8];
        short8 b1 = *(const short8*)&sT[col][32 + lg * 8];
        float csacc = 0.f;
        for (int mt = 0; mt < 6; ++mt) {
            if (mt * 16 >= mc) break;  // mc uniform per block
            short8 a0 = *(const short8*)&hT[mt * 16 + lr][lg * 8];
            short8 a1 = *(const short8*)&hT[mt * 16 + lr][32 + lg * 8];
            f32x4 acc = {0.f, 0.f, 0.f, 0.f};
            acc = MFMA16(a0, b0, acc);
            acc = MFMA16(a1, b1, acc);
            #pragma unroll
            for (int v = 0; v < 4; ++v) {
                float x = acc[v];
                x = fminf(fmaxf(x, -15.f), 15.f);
                float e = __expf(2.f * x);
                float t = (e - 1.f) / (e + 1.f);  // tanh; pad entries give tanh(0)=0
                csacc += t;
                float rv = t;
                rv += __shfl_xor(rv, 1); rv += __shfl_xor(rv, 2);
                rv += __shfl_xor(rv, 4); rv += __shfl_xor(rv, 8);
                if (lr == 0) atomicAdd(&rs[mt * 16 + lg * 4 + v], rv);
            }
        }
        atomicAdd(&cs[col], csacc);
    }
    __syncthreads();  // B2
    float p1 = 0.f, p3 = 0.f;
    for (int n = w; n < LSOLV; n += 4) p1 += cs[n] * bf2f(sT[n][d]);
    for (int m = w; m < LMOL; m += 4) p3 += rs[m] * bf2f(hT[m][d]);
    atomicAdd(&zz[64 + d], p1);
    atomicAdd(&zz[192 + d], p3);
    __syncthreads();  // B3
    Z[(size_t)g * 256 + tid] = zz[tid];
}

// ---------------- MLP: out = relu(z @ l1W + l1b) @ l2W + l2b ----------------
__global__ __launch_bounds__(256) void mlp_kernel(const float* __restrict__ Z,
                                                  const float* __restrict__ l1W,
                                                  const float* __restrict__ l1b,
                                                  const float* __restrict__ l2W,
                                                  const float* __restrict__ l2b,
                                                  float* __restrict__ out) {
    __shared__ float zl[16 * 256];
    __shared__ float red[64];
    int g0 = blockIdx.x * 16;
    int tid = threadIdx.x;
    for (int idx = tid; idx < 16 * 256; idx += 256) zl[idx] = Z[(size_t)g0 * 256 + idx];
    __syncthreads();
    float hid[16];
    float b = l1b[tid];
    #pragma unroll
    for (int t = 0; t < 16; ++t) hid[t] = b;
    for (int k = 0; k < 256; ++k) {
        float wv = l1W[k * 256 + tid];
        #pragma unroll
        for (int t = 0; t < 16; ++t) hid[t] += zl[t * 256 + k] * wv;
    }
    float w2 = l2W[tid];
    int lane = tid & 63, wv4 = tid >> 6;
    #pragma unroll
    for (int t = 0; t < 16; ++t) {
        float v = fmaxf(hid[t], 0.f) * w2;
        for (int off = 32; off; off >>= 1) v += __shfl_xor(v, off);
        if (lane == 0) red[wv4 * 16 + t] = v;
    }
    __syncthreads();
    if (tid < 16) out[g0 + tid] = red[tid] + red[16 + tid] + red[32 + tid] + red[48 + tid] + l2b[0];
}

extern "C" void kernel_launch(void* const* d_in, const int* in_sizes, int n_in,
                              void* d_out, int out_size, void* d_ws, size_t ws_size,
                              hipStream_t stream) {
    const float* h     = (const float*)d_in[0];
    const float* sfeat = (const float*)d_in[1];
    const float* embW  = (const float*)d_in[2];
    const float* embB  = (const float*)d_in[3];
    const float* gcnW  = (const float*)d_in[4];
    const float* gcnB  = (const float*)d_in[5];
    const float* hW    = (const float*)d_in[6];
    const float* sW    = (const float*)d_in[7];
    const float* bnhg  = (const float*)d_in[8];
    const float* bnhb  = (const float*)d_in[9];
    const float* bnsg  = (const float*)d_in[10];
    const float* bnsb  = (const float*)d_in[11];
    const float* l1W   = (const float*)d_in[12];
    const float* l1b   = (const float*)d_in[13];
    const float* l2W   = (const float*)d_in[14];
    const float* l2b   = (const float*)d_in[15];
    const int* mseg = (const int*)d_in[16];
    const int* mpos = (const int*)d_in[17];
    const int* sseg = (const int*)d_in[18];
    const int* spos = (const int*)d_in[19];

    int Nm = in_sizes[0] / HID;
    int Ns = in_sizes[1] / NODE_DIM;
    int NB = out_size;  // 4096 graphs (TGT==1)

    float* ws     = (float*)d_ws;
    float* yh     = ws;                          // [Nm][64]; prefix [Ns][64] doubles as embed out
    float* hsbuf  = ws;                          // alias (embed out, consumed before yh written)
    float* ysbuf  = yh + (size_t)Nm * HID;       // [Ns][64]
    float* hs_red = ysbuf + (size_t)Ns * HID;    // [NB][64]
    float* Z      = hs_red + (size_t)NB * 64;    // [NB][256]
    int*   moff   = (int*)(Z + (size_t)NB * 256);
    int*   soff   = moff + NB;
    int*   mcnt   = soff + NB;
    int*   scnt   = mcnt + NB;
    float* partH  = (float*)(scnt + NB);         // [NPART][128]
    float* sumP   = partH + (size_t)NPART * 128; // [64][128]
    float* statsbuf = sumP + 64 * 128;           // [256]

    hipMemsetAsync(mcnt, 0, 2 * (size_t)NB * sizeof(int), stream);
    hipMemsetAsync(sumP, 0, 64 * 128 * sizeof(float), stream);
    int nmax = Nm > Ns ? Nm : Ns;
    offsets_kernel<<<(nmax + 255) / 256, 256, 0, stream>>>(mseg, mpos, Nm, sseg, spos, Ns,
                                                           moff, soff, mcnt, scnt);
    int gblk = (Ns + 63) / 64;
    embed_mfma_kernel<<<gblk, 256, 0, stream>>>(sfeat, embW, embB, hsbuf, Ns);
    gcn_fused_kernel<<<NB, 256, 0, stream>>>(hsbuf, gcnW, gcnB, sW, soff, scnt,
                                             ysbuf, hs_red, sumP);
    stats_mfma_kernel<<<NPART, 256, 0, stream>>>(h, hW, Nm, yh, partH);
    finalize_kernel<<<1, 1024, 0, stream>>>(partH, NPART, sumP,
                                            bnhg, bnhb, bnsg, bnsb, Nm, Ns, statsbuf);
    interact_kernel<<<NB, 256, 0, stream>>>(h, yh, ysbuf, hs_red, statsbuf,
                                            moff, mcnt, soff, scnt, Z);
    mlp_kernel<<<NB / 16, 256, 0, stream>>>(Z, l1W, l1b, l2W, l2b, (float*)d_out);
}